// Round 1
// baseline (206.259 us; speedup 1.0000x reference)
//
#include <hip/hip_runtime.h>

#define N_STK 768
#define BATCH 2
#define WIN   32
#define FEAT  4
#define UNITS 32
#define G4    128     // 4*UNITS gate rows
#define INP   72      // 2U + K
#define PADW  76      // LDS row stride (float4-aligned, breaks bank conflicts)

__device__ __forceinline__ float sigmoidf(float x){ return 1.0f/(1.0f + __expf(-x)); }
__device__ __forceinline__ float lrelu(float v){ return v > 0.0f ? v : 0.01f*v; }

// ---------------------------------------------------------------------------
// 1) Pattern + inverse-degree precompute.
//    rel_encoding values are exactly {0,1}; pat = 8-bit nonzero mask per (i,j).
//    D[i] = #j with pat!=0 (self loops guarantee >=1).
__global__ __launch_bounds__(256) void pattern_kernel(const float* __restrict__ rel,
                                                      unsigned char* __restrict__ P,
                                                      float* __restrict__ invD){
    int i = blockIdx.x;
    __shared__ int cnt;
    if (threadIdx.x == 0) cnt = 0;
    __syncthreads();
    int local = 0;
    for (int j = threadIdx.x; j < N_STK; j += 256){
        const float4* r4 = reinterpret_cast<const float4*>(rel + ((size_t)i*N_STK + j)*8);
        float4 a = r4[0], b = r4[1];
        unsigned pat = 0;
        pat |= (a.x != 0.0f) ? 1u   : 0u;
        pat |= (a.y != 0.0f) ? 2u   : 0u;
        pat |= (a.z != 0.0f) ? 4u   : 0u;
        pat |= (a.w != 0.0f) ? 8u   : 0u;
        pat |= (b.x != 0.0f) ? 16u  : 0u;
        pat |= (b.y != 0.0f) ? 32u  : 0u;
        pat |= (b.z != 0.0f) ? 64u  : 0u;
        pat |= (b.w != 0.0f) ? 128u : 0u;
        P[(size_t)i*N_STK + j] = (unsigned char)pat;
        local += (pat != 0u) ? 1 : 0;
    }
    atomicAdd(&cnt, local);
    __syncthreads();
    if (threadIdx.x == 0) invD[i] = 1.0f/(float)cnt;
}

// ---------------------------------------------------------------------------
// 2) Build split LUTs per hop: lo[m][p] = b1[p] + sum_{q<4,bit} W1[64+q][p]
//                              hi[m][p] =         sum_{q<4,bit} W1[68+q][p]
__global__ void lut_kernel(const float* __restrict__ hop_w1, const float* __restrict__ hop_b1,
                           float* __restrict__ lutlo, float* __restrict__ luthi){
    int idx = blockIdx.x*blockDim.x + threadIdx.x;
    if (idx >= 2*2*16*INP) return;
    int p = idx % INP;
    int r = idx / INP;
    int m = r & 15; r >>= 4;
    int half = r & 1; int k = r >> 1;
    const float* W = hop_w1 + (size_t)k*INP*INP;
    float acc = half ? 0.0f : hop_b1[k*INP + p];
    int base = 2*UNITS + (half ? 4 : 0);
    #pragma unroll
    for (int q = 0; q < 4; q++)
        if ((m >> q) & 1) acc += W[(base+q)*INP + p];
    float* dst = half ? luthi : lutlo;
    dst[(k*16 + m)*INP + p] = acc;
}

// ---------------------------------------------------------------------------
// 3) LSTM over window, last hidden state. 8 sequences/block, 32 lanes each.
//    WhhT stored [u][row] so lanes (row index) hit consecutive banks.
__global__ __launch_bounds__(256) void lstm_kernel(const float* __restrict__ x,
        const float* __restrict__ Wih, const float* __restrict__ Whh,
        const float* __restrict__ bih, const float* __restrict__ bhh,
        float* __restrict__ seq){
    __shared__ float WhhT[UNITS][G4];      // 16 KB
    __shared__ float Wih_sh[G4][FEAT];
    __shared__ float bias_sh[G4];
    __shared__ float h_sh[8][UNITS];
    int tid = threadIdx.x;
    for (int idx = tid; idx < G4*UNITS; idx += 256){
        int g = idx >> 5, u = idx & 31;
        WhhT[u][g] = Whh[idx];             // Whh[g*32+u]
    }
    for (int idx = tid; idx < G4*FEAT; idx += 256) Wih_sh[idx>>2][idx&3] = Wih[idx];
    if (tid < G4) bias_sh[tid] = bih[tid] + bhh[tid];
    int sl = tid >> 5, jj = tid & 31;
    int m = blockIdx.x*8 + sl;             // 0..1535
    int b = m / N_STK, n = m % N_STK;
    h_sh[sl][jj] = 0.0f;
    float c = 0.0f, hcur = 0.0f;
    __syncthreads();
    for (int t = 0; t < WIN; t++){
        float4 xv = *reinterpret_cast<const float4*>(x + ((size_t)(b*WIN + t)*N_STK + n)*FEAT);
        float z0 = bias_sh[jj]       + Wih_sh[jj][0]*xv.x       + Wih_sh[jj][1]*xv.y       + Wih_sh[jj][2]*xv.z       + Wih_sh[jj][3]*xv.w;
        float z1 = bias_sh[32+jj]    + Wih_sh[32+jj][0]*xv.x    + Wih_sh[32+jj][1]*xv.y    + Wih_sh[32+jj][2]*xv.z    + Wih_sh[32+jj][3]*xv.w;
        float z2 = bias_sh[64+jj]    + Wih_sh[64+jj][0]*xv.x    + Wih_sh[64+jj][1]*xv.y    + Wih_sh[64+jj][2]*xv.z    + Wih_sh[64+jj][3]*xv.w;
        float z3 = bias_sh[96+jj]    + Wih_sh[96+jj][0]*xv.x    + Wih_sh[96+jj][1]*xv.y    + Wih_sh[96+jj][2]*xv.z    + Wih_sh[96+jj][3]*xv.w;
        #pragma unroll
        for (int u = 0; u < UNITS; u++){
            float hu = h_sh[sl][u];
            z0 += WhhT[u][jj]      * hu;
            z1 += WhhT[u][32+jj]   * hu;
            z2 += WhhT[u][64+jj]   * hu;
            z3 += WhhT[u][96+jj]   * hu;
        }
        float ig = sigmoidf(z0), fg = sigmoidf(z1), gg = tanhf(z2), og = sigmoidf(z3);
        c = fg*c + ig*gg;
        hcur = og * tanhf(c);
        __syncthreads();
        h_sh[sl][jj] = hcur;
        __syncthreads();
    }
    seq[(size_t)m*UNITS + jj] = hcur;
}

// ---------------------------------------------------------------------------
// 4a) xi = e @ W1[:U], xj = e @ W1[U:2U]   per hop.
__global__ __launch_bounds__(256) void xixj_kernel(const float* __restrict__ ein,
        const float* __restrict__ W1, float* __restrict__ xi, float* __restrict__ xj){
    int idx = blockIdx.x*blockDim.x + threadIdx.x;
    if (idx >= BATCH*N_STK*INP) return;
    int p = idx % INP;
    int bn = idx / INP;
    const float* e = ein + (size_t)bn*UNITS;
    float si = 0.0f, sj = 0.0f;
    #pragma unroll
    for (int u = 0; u < UNITS; u++){
        float ev = e[u];
        si += ev * W1[u*INP + p];
        sj += ev * W1[(UNITS+u)*INP + p];
    }
    xi[idx] = si; xj[idx] = sj;
}

// ---------------------------------------------------------------------------
// 4b) The dominant kernel: 16x16 pair tiles per block, full INP loop unrolled
//     as 18 float4 steps, all operands staged in LDS (19.8 KB -> 8 blocks/CU).
//     s[b,j] += lrelu(dot(lrelu(xi+xj+lut),w2)+b2)/D[i], reduced over tile i
//     via shfl then one atomic per (tile, j).
__global__ __launch_bounds__(256) void pair_kernel(const float* __restrict__ xi,
        const float* __restrict__ xj,
        const float* __restrict__ lutlo_k, const float* __restrict__ luthi_k,
        const float* __restrict__ w2, const float* __restrict__ b2,
        const unsigned char* __restrict__ P, const float* __restrict__ invD,
        float* __restrict__ s_out){
    __shared__ float xi_sh[16*PADW];
    __shared__ float xj_sh[16*PADW];
    __shared__ float lo_sh[16*PADW];
    __shared__ float hi_sh[16*PADW];
    __shared__ float w2_sh[PADW];
    int tid = threadIdx.x;
    int b = blockIdx.z;
    int i0 = blockIdx.x*16, j0 = blockIdx.y*16;
    const float* xiB = xi + ((size_t)b*N_STK + i0)*INP;
    const float* xjB = xj + ((size_t)b*N_STK + j0)*INP;
    for (int t = tid; t < 16*18; t += 256){
        int row = t/18, c4 = (t%18)*4;
        *reinterpret_cast<float4*>(&xi_sh[row*PADW + c4]) = *reinterpret_cast<const float4*>(xiB      + row*INP + c4);
        *reinterpret_cast<float4*>(&xj_sh[row*PADW + c4]) = *reinterpret_cast<const float4*>(xjB      + row*INP + c4);
        *reinterpret_cast<float4*>(&lo_sh[row*PADW + c4]) = *reinterpret_cast<const float4*>(lutlo_k  + row*INP + c4);
        *reinterpret_cast<float4*>(&hi_sh[row*PADW + c4]) = *reinterpret_cast<const float4*>(luthi_k  + row*INP + c4);
    }
    if (tid < 18) *reinterpret_cast<float4*>(&w2_sh[tid*4]) = *reinterpret_cast<const float4*>(w2 + tid*4);
    __syncthreads();
    int ti = tid & 15, tj = tid >> 4;
    int i = i0 + ti, j = j0 + tj;
    unsigned pat = P[(size_t)i*N_STK + j];
    float contrib = 0.0f;
    if (pat){
        const float* xiR = &xi_sh[ti*PADW];
        const float* xjR = &xj_sh[tj*PADW];
        const float* loR = &lo_sh[(pat & 15u)*PADW];
        const float* hiR = &hi_sh[(pat >> 4)*PADW];
        float acc = 0.0f;
        #pragma unroll
        for (int q = 0; q < 18; q++){
            float4 a  = *reinterpret_cast<const float4*>(xiR + q*4);
            float4 bb = *reinterpret_cast<const float4*>(xjR + q*4);
            float4 l  = *reinterpret_cast<const float4*>(loR + q*4);
            float4 h  = *reinterpret_cast<const float4*>(hiR + q*4);
            float4 w  = *reinterpret_cast<const float4*>(&w2_sh[q*4]);
            acc += lrelu(a.x + bb.x + l.x + h.x) * w.x;
            acc += lrelu(a.y + bb.y + l.y + h.y) * w.y;
            acc += lrelu(a.z + bb.z + l.z + h.z) * w.z;
            acc += lrelu(a.w + bb.w + l.w + h.w) * w.w;
        }
        float wv = lrelu(acc + b2[0]);
        contrib = wv * invD[i];
    }
    contrib += __shfl_xor(contrib, 1);
    contrib += __shfl_xor(contrib, 2);
    contrib += __shfl_xor(contrib, 4);
    contrib += __shfl_xor(contrib, 8);
    if (ti == 0) atomicAdd(&s_out[b*N_STK + j], contrib);
}

// ---------------------------------------------------------------------------
// 4c) e_out[b,j,:] = s[b,j] * e_in[b,j,:]
__global__ void scale_kernel(const float* __restrict__ ein, const float* __restrict__ s,
                             float* __restrict__ eout){
    int idx = blockIdx.x*blockDim.x + threadIdx.x;
    if (idx >= BATCH*N_STK*UNITS) return;
    eout[idx] = ein[idx] * s[idx/UNITS];
}

// ---------------------------------------------------------------------------
// 5) FullyConnected head: one 64-lane wave per (b,n).
__global__ __launch_bounds__(64) void head_kernel(const float* __restrict__ seq,
        const float* __restrict__ e,
        const float* __restrict__ w1, const float* __restrict__ b1,
        const float* __restrict__ w2, const float* __restrict__ b2,
        float* __restrict__ out){
    __shared__ float comb[64];
    int bn = blockIdx.x, tid = threadIdx.x;
    comb[tid] = (tid < 32) ? seq[(size_t)bn*32 + tid] : e[(size_t)bn*32 + (tid - 32)];
    __syncthreads();
    float acc = b1[tid];
    #pragma unroll 8
    for (int d = 0; d < 64; d++) acc += comb[d] * w1[d*64 + tid];
    float prod = lrelu(acc) * w2[tid];
    prod += __shfl_xor(prod, 32);
    prod += __shfl_xor(prod, 16);
    prod += __shfl_xor(prod, 8);
    prod += __shfl_xor(prod, 4);
    prod += __shfl_xor(prod, 2);
    prod += __shfl_xor(prod, 1);
    if (tid == 0) out[bn] = lrelu(prod + b2[0]);
}

// ---------------------------------------------------------------------------
extern "C" void kernel_launch(void* const* d_in, const int* in_sizes, int n_in,
                              void* d_out, int out_size, void* d_ws, size_t ws_size,
                              hipStream_t stream){
    const float* input_data = (const float*)d_in[0];
    const float* rel        = (const float*)d_in[1];
    const float* lstm_Wih   = (const float*)d_in[2];
    const float* lstm_Whh   = (const float*)d_in[3];
    const float* lstm_bih   = (const float*)d_in[4];
    const float* lstm_bhh   = (const float*)d_in[5];
    const float* hop_w1     = (const float*)d_in[6];
    const float* hop_b1     = (const float*)d_in[7];
    const float* hop_w2     = (const float*)d_in[8];
    const float* hop_b2     = (const float*)d_in[9];
    const float* fn_w1      = (const float*)d_in[10];
    const float* fn_b1      = (const float*)d_in[11];
    const float* fn_w2      = (const float*)d_in[12];
    const float* fn_b2      = (const float*)d_in[13];
    float* out = (float*)d_out;

    // workspace layout (floats)
    float* ws    = (float*)d_ws;
    float* seq   = ws;                    // 2*768*32 = 49152
    float* eA    = seq  + 49152;
    float* eB    = eA   + 49152;
    float* xi    = eB   + 49152;          // 2*768*72 = 110592
    float* xj    = xi   + 110592;
    float* s     = xj   + 110592;         // 1536
    float* invD  = s    + 1536;           // 768
    float* lutlo = invD + 768;            // 2*16*72 = 2304
    float* luthi = lutlo + 2304;          // 2304
    unsigned char* P = (unsigned char*)(luthi + 2304);   // 768*768 bytes

    pattern_kernel<<<N_STK, 256, 0, stream>>>(rel, P, invD);
    lut_kernel<<<(2*2*16*INP + 255)/256, 256, 0, stream>>>(hop_w1, hop_b1, lutlo, luthi);
    lstm_kernel<<<(BATCH*N_STK)/8, 256, 0, stream>>>(input_data, lstm_Wih, lstm_Whh,
                                                     lstm_bih, lstm_bhh, seq);

    const float* ein = seq;
    float* eout = eA;
    for (int k = 0; k < 2; k++){
        hipMemsetAsync(s, 0, BATCH*N_STK*sizeof(float), stream);
        xixj_kernel<<<(BATCH*N_STK*INP + 255)/256, 256, 0, stream>>>(ein, hop_w1 + k*INP*INP, xi, xj);
        dim3 grid(N_STK/16, N_STK/16, BATCH);
        pair_kernel<<<grid, 256, 0, stream>>>(xi, xj, lutlo + k*16*INP, luthi + k*16*INP,
                                              hop_w2 + k*INP, hop_b2 + k, P, invD, s);
        scale_kernel<<<(BATCH*N_STK*UNITS + 255)/256, 256, 0, stream>>>(ein, s, eout);
        ein = eout;
        eout = eB;
    }
    head_kernel<<<BATCH*N_STK, 64, 0, stream>>>(seq, ein, fn_w1, fn_b1, fn_w2, fn_b2, out);
}

// Round 2
// 204.182 us; speedup vs baseline: 1.0102x; 1.0102x over previous
//
#include <hip/hip_runtime.h>

#define N_STK 768
#define BATCH 2
#define WIN   32
#define FEAT  4
#define UNITS 32
#define G4    128     // 4*UNITS gate rows
#define INP   72      // 2U + K
#define PADW  76      // LDS row stride: 76/4=19 (odd) spreads 16 rows over all 8 bank-quads

__device__ __forceinline__ float lrelu(float v){ return v > 0.0f ? v : 0.01f*v; }
__device__ __forceinline__ float lanebcast(float v, int l){
    return __int_as_float(__builtin_amdgcn_readlane(__float_as_int(v), l));
}

// ---------------------------------------------------------------------------
// 1) Pattern + inverse-degree precompute (row-wise, coalesced).
//    rel_encoding values are exactly {0,1}; pat = 8-bit nonzero mask per (i,j).
__global__ __launch_bounds__(256) void pattern_kernel(const float* __restrict__ rel,
                                                      unsigned char* __restrict__ P,
                                                      float* __restrict__ invD){
    int i = blockIdx.x;
    __shared__ int cnt;
    if (threadIdx.x == 0) cnt = 0;
    __syncthreads();
    int local = 0;
    for (int j = threadIdx.x; j < N_STK; j += 256){
        const float4* r4 = reinterpret_cast<const float4*>(rel + ((size_t)i*N_STK + j)*8);
        float4 a = r4[0], b = r4[1];
        unsigned pat = 0;
        pat |= (a.x != 0.0f) ? 1u   : 0u;
        pat |= (a.y != 0.0f) ? 2u   : 0u;
        pat |= (a.z != 0.0f) ? 4u   : 0u;
        pat |= (a.w != 0.0f) ? 8u   : 0u;
        pat |= (b.x != 0.0f) ? 16u  : 0u;
        pat |= (b.y != 0.0f) ? 32u  : 0u;
        pat |= (b.z != 0.0f) ? 64u  : 0u;
        pat |= (b.w != 0.0f) ? 128u : 0u;
        P[(size_t)i*N_STK + j] = (unsigned char)pat;
        local += (pat != 0u) ? 1 : 0;
    }
    atomicAdd(&cnt, local);
    __syncthreads();
    if (threadIdx.x == 0) invD[i] = 1.0f/(float)cnt;
}

// ---------------------------------------------------------------------------
// 2) CSC compaction: block per column j, ordered by i (deterministic sums).
//    Each thread owns 3 consecutive i's; block-wide inclusive scan gives slots.
__global__ __launch_bounds__(256) void csc_kernel(const unsigned char* __restrict__ P,
                                                  unsigned* __restrict__ list,
                                                  int* __restrict__ cnt){
    int j = blockIdx.x, t = threadIdx.x;
    unsigned char pv[3];
    int c = 0;
    #pragma unroll
    for (int r = 0; r < 3; r++){
        pv[r] = P[(size_t)(t*3 + r)*N_STK + j];
        c += (pv[r] != 0) ? 1 : 0;
    }
    __shared__ int sc[256];
    sc[t] = c;
    __syncthreads();
    for (int off = 1; off < 256; off <<= 1){
        int v = 0;
        if (t >= off) v = sc[t - off];
        __syncthreads();
        sc[t] += v;
        __syncthreads();
    }
    int slot = sc[t] - c;   // exclusive prefix
    #pragma unroll
    for (int r = 0; r < 3; r++){
        if (pv[r]) list[(size_t)j*N_STK + (slot++)] = (unsigned)(((t*3 + r) << 8) | pv[r]);
    }
    if (t == 0) cnt[j] = sc[255];
}

// ---------------------------------------------------------------------------
// 3) LUTs per hop: lo[m][p] = b1[p] + sum_{q<4,bit} W1[64+q][p] ; hi analog.
__global__ void lut_kernel(const float* __restrict__ hop_w1, const float* __restrict__ hop_b1,
                           float* __restrict__ lutlo, float* __restrict__ luthi){
    int idx = blockIdx.x*blockDim.x + threadIdx.x;
    if (idx >= 2*2*16*INP) return;
    int p = idx % INP;
    int r = idx / INP;
    int m = r & 15; r >>= 4;
    int half = r & 1; int k = r >> 1;
    const float* W = hop_w1 + (size_t)k*INP*INP;
    float acc = half ? 0.0f : hop_b1[k*INP + p];
    int base = 2*UNITS + (half ? 4 : 0);
    #pragma unroll
    for (int q = 0; q < 4; q++)
        if ((m >> q) & 1) acc += W[(base+q)*INP + p];
    float* dst = half ? luthi : lutlo;
    dst[(k*16 + m)*INP + p] = acc;
}

// ---------------------------------------------------------------------------
// 4) LSTM: ONE SEQUENCE PER WAVE64. No LDS, no barriers.
//    Lane l owns gate rows r0=l and r1=64+l:
//      l<32 : r0 = i-gate(unit l), r1 = g-gate(unit l)
//      l>=32: r0 = f-gate(unit l-32), r1 = o-gate(unit l-32)
//    h[u] lives in lane 32+u; broadcast via v_readlane (const lane idx).
//    Cross-half product sig(i)*tanh(g) moves via one shfl_xor(·,32).
__global__ __launch_bounds__(256) void lstm_kernel(const float* __restrict__ x,
        const float* __restrict__ Wih, const float* __restrict__ Whh,
        const float* __restrict__ bih, const float* __restrict__ bhh,
        float* __restrict__ seq){
    int lane = threadIdx.x & 63;
    int m = blockIdx.x*4 + (threadIdx.x >> 6);   // sequence id, 0..1535
    int b = m / N_STK, n = m % N_STK;
    int r0 = lane, r1 = 64 + lane;
    bool low = (lane < 32);

    // per-lane weights in registers
    float4 wi0 = *reinterpret_cast<const float4*>(Wih + r0*FEAT);
    float4 wi1 = *reinterpret_cast<const float4*>(Wih + r1*FEAT);
    float bb0 = bih[r0] + bhh[r0];
    float bb1 = bih[r1] + bhh[r1];
    float4 W0[8], W1[8];
    #pragma unroll
    for (int q = 0; q < 8; q++){
        W0[q] = *reinterpret_cast<const float4*>(Whh + r0*UNITS + q*4);
        W1[q] = *reinterpret_cast<const float4*>(Whh + r1*UNITS + q*4);
    }
    // prefetch all timesteps: lane t<32 holds x[b,t,n,:]
    float4 xv = make_float4(0.f, 0.f, 0.f, 0.f);
    if (low) xv = *reinterpret_cast<const float4*>(x + ((size_t)(b*WIN + lane)*N_STK + n)*FEAT);

    float hreg = 0.0f, c = 0.0f;
    #pragma unroll 1
    for (int t = 0; t < WIN; t++){
        float xb0 = lanebcast(xv.x, t), xb1 = lanebcast(xv.y, t);
        float xb2 = lanebcast(xv.z, t), xb3 = lanebcast(xv.w, t);
        float z0a = bb0 + wi0.x*xb0 + wi0.z*xb2;
        float z0b =       wi0.y*xb1 + wi0.w*xb3;
        float z1a = bb1 + wi1.x*xb0 + wi1.z*xb2;
        float z1b =       wi1.y*xb1 + wi1.w*xb3;
        #pragma unroll
        for (int q = 0; q < 8; q++){
            float h0 = lanebcast(hreg, 32 + q*4 + 0);
            float h1 = lanebcast(hreg, 32 + q*4 + 1);
            float h2 = lanebcast(hreg, 32 + q*4 + 2);
            float h3 = lanebcast(hreg, 32 + q*4 + 3);
            z0a += W0[q].x*h0; z0b += W0[q].y*h1;
            z0a += W0[q].z*h2; z0b += W0[q].w*h3;
            z1a += W1[q].x*h0; z1b += W1[q].y*h1;
            z1a += W1[q].z*h2; z1b += W1[q].w*h3;
        }
        float z0 = z0a + z0b, z1 = z1a + z1b;
        float e0 = __expf(-z0);
        float s0 = 1.0f/(1.0f + e0);                 // sig(i) / sig(f)
        float sc = low ? -2.0f : -1.0f;
        float e1 = __expf(sc*z1);
        float rr = 1.0f/(1.0f + e1);
        float act = low ? (1.0f - e1)*rr : rr;       // tanh(g) / sig(o)
        float pa = s0*act;                            // lower: sig(i)*tanh(g)
        float po = __shfl_xor(pa, 32);
        c = s0*c + po;                                // upper: sig(f)*c + i*g
        float e2 = __expf(-2.0f*c);
        float th = (1.0f - e2)/(1.0f + e2);           // tanh(c)
        hreg = act*th;                                // upper: sig(o)*tanh(c)
    }
    if (!low) seq[(size_t)m*UNITS + (lane - 32)] = hreg;
}

// ---------------------------------------------------------------------------
// 5a) xi = e @ W1[:U], xj = e @ W1[U:2U]   per hop.
__global__ __launch_bounds__(256) void xixj_kernel(const float* __restrict__ ein,
        const float* __restrict__ W1, float* __restrict__ xi, float* __restrict__ xj){
    int idx = blockIdx.x*blockDim.x + threadIdx.x;
    if (idx >= BATCH*N_STK*INP) return;
    int p = idx % INP;
    int bn = idx / INP;
    const float* e = ein + (size_t)bn*UNITS;
    float si = 0.0f, sj = 0.0f;
    #pragma unroll
    for (int u = 0; u < UNITS; u++){
        float ev = e[u];
        si += ev * W1[u*INP + p];
        sj += ev * W1[(UNITS+u)*INP + p];
    }
    xi[idx] = si; xj[idx] = sj;
}

// ---------------------------------------------------------------------------
// 5b) Sparse column kernel: one block per column j; both batches.
//     s[b,j] = sum over nonzero (i,pat) of lrelu(dot(lrelu(xi_i+xj_j+lut_pat),w2)+b2)/D_i
//     then epilogue eout[b,j,:] = ein[b,j,:]*s[b,j]. No atomics, no memset.
__global__ __launch_bounds__(256) void col_kernel(const float* __restrict__ xi,
        const float* __restrict__ xj,
        const float* __restrict__ lutlo_k, const float* __restrict__ luthi_k,
        const float* __restrict__ w2, const float* __restrict__ b2,
        const unsigned* __restrict__ list, const int* __restrict__ cnt,
        const float* __restrict__ invD,
        const float* __restrict__ ein, float* __restrict__ eout){
    int j = blockIdx.x, tid = threadIdx.x;
    int cn = cnt[j];
    __shared__ float xjlo_sh[2][16][PADW];   // xj[b,j,:] + lutlo[m,:]
    __shared__ float hi_sh[16][PADW];
    __shared__ float red0[4], red1[4];
    __shared__ float sval[2];
    for (int idx = tid; idx < 16*INP; idx += 256){
        int m = idx / INP, p = idx % INP;
        float lo = lutlo_k[m*INP + p];
        xjlo_sh[0][m][p] = lo + xj[((size_t)0*N_STK + j)*INP + p];
        xjlo_sh[1][m][p] = lo + xj[((size_t)1*N_STK + j)*INP + p];
        hi_sh[m][p] = luthi_k[m*INP + p];
    }
    float4 w2r[18];
    #pragma unroll
    for (int q = 0; q < 18; q++) w2r[q] = *reinterpret_cast<const float4*>(w2 + q*4);
    float b2v = b2[0];
    __syncthreads();

    float acc0 = 0.0f, acc1 = 0.0f;
    for (int p = tid; p < cn; p += 256){
        unsigned ent = list[(size_t)j*N_STK + p];
        int i = (int)(ent >> 8);
        int mlo = (int)(ent & 15u), mhi = (int)((ent >> 4) & 15u);
        float id = invD[i];
        const float* xi0 = xi + ((size_t)0*N_STK + i)*INP;
        const float* xi1 = xi + ((size_t)1*N_STK + i)*INP;
        const float* jl0 = &xjlo_sh[0][mlo][0];
        const float* jl1 = &xjlo_sh[1][mlo][0];
        const float* hh  = &hi_sh[mhi][0];
        float4 a0 = make_float4(0.f,0.f,0.f,0.f);
        float4 a1 = make_float4(0.f,0.f,0.f,0.f);
        #pragma unroll
        for (int q = 0; q < 18; q++){
            float4 h4 = *reinterpret_cast<const float4*>(hh + q*4);
            float4 x0 = *reinterpret_cast<const float4*>(xi0 + q*4);
            float4 j0 = *reinterpret_cast<const float4*>(jl0 + q*4);
            float4 x1 = *reinterpret_cast<const float4*>(xi1 + q*4);
            float4 j1 = *reinterpret_cast<const float4*>(jl1 + q*4);
            float4 w  = w2r[q];
            a0.x += lrelu(x0.x + j0.x + h4.x)*w.x;
            a0.y += lrelu(x0.y + j0.y + h4.y)*w.y;
            a0.z += lrelu(x0.z + j0.z + h4.z)*w.z;
            a0.w += lrelu(x0.w + j0.w + h4.w)*w.w;
            a1.x += lrelu(x1.x + j1.x + h4.x)*w.x;
            a1.y += lrelu(x1.y + j1.y + h4.y)*w.y;
            a1.z += lrelu(x1.z + j1.z + h4.z)*w.z;
            a1.w += lrelu(x1.w + j1.w + h4.w)*w.w;
        }
        acc0 += lrelu(a0.x + a0.y + a0.z + a0.w + b2v)*id;
        acc1 += lrelu(a1.x + a1.y + a1.z + a1.w + b2v)*id;
    }
    #pragma unroll
    for (int d = 1; d < 64; d <<= 1){
        acc0 += __shfl_xor(acc0, d);
        acc1 += __shfl_xor(acc1, d);
    }
    if ((tid & 63) == 0){ red0[tid >> 6] = acc0; red1[tid >> 6] = acc1; }
    __syncthreads();
    if (tid == 0){
        sval[0] = red0[0] + red0[1] + red0[2] + red0[3];
        sval[1] = red1[0] + red1[1] + red1[2] + red1[3];
    }
    __syncthreads();
    if (tid < 64){
        int b = tid >> 5, u = tid & 31;
        size_t o = ((size_t)b*N_STK + j)*UNITS + u;
        eout[o] = ein[o]*sval[b];
    }
}

// ---------------------------------------------------------------------------
// 6) FullyConnected head: one 64-lane wave per (b,n).
__global__ __launch_bounds__(64) void head_kernel(const float* __restrict__ seq,
        const float* __restrict__ e,
        const float* __restrict__ w1, const float* __restrict__ b1,
        const float* __restrict__ w2, const float* __restrict__ b2,
        float* __restrict__ out){
    __shared__ float comb[64];
    int bn = blockIdx.x, tid = threadIdx.x;
    comb[tid] = (tid < 32) ? seq[(size_t)bn*32 + tid] : e[(size_t)bn*32 + (tid - 32)];
    __syncthreads();
    float acc = b1[tid];
    #pragma unroll 8
    for (int d = 0; d < 64; d++) acc += comb[d] * w1[d*64 + tid];
    float prod = lrelu(acc) * w2[tid];
    prod += __shfl_xor(prod, 32);
    prod += __shfl_xor(prod, 16);
    prod += __shfl_xor(prod, 8);
    prod += __shfl_xor(prod, 4);
    prod += __shfl_xor(prod, 2);
    prod += __shfl_xor(prod, 1);
    if (tid == 0) out[bn] = lrelu(prod + b2[0]);
}

// ---------------------------------------------------------------------------
extern "C" void kernel_launch(void* const* d_in, const int* in_sizes, int n_in,
                              void* d_out, int out_size, void* d_ws, size_t ws_size,
                              hipStream_t stream){
    const float* input_data = (const float*)d_in[0];
    const float* rel        = (const float*)d_in[1];
    const float* lstm_Wih   = (const float*)d_in[2];
    const float* lstm_Whh   = (const float*)d_in[3];
    const float* lstm_bih   = (const float*)d_in[4];
    const float* lstm_bhh   = (const float*)d_in[5];
    const float* hop_w1     = (const float*)d_in[6];
    const float* hop_b1     = (const float*)d_in[7];
    const float* hop_w2     = (const float*)d_in[8];
    const float* hop_b2     = (const float*)d_in[9];
    const float* fn_w1      = (const float*)d_in[10];
    const float* fn_b1      = (const float*)d_in[11];
    const float* fn_w2      = (const float*)d_in[12];
    const float* fn_b2      = (const float*)d_in[13];
    float* out = (float*)d_out;

    // workspace layout (floats; every chunk 16B-aligned)
    float* ws    = (float*)d_ws;
    float* seq   = ws;                    // 49152
    float* eA    = seq   + 49152;
    float* eB    = eA    + 49152;
    float* xi    = eB    + 49152;         // 110592
    float* xj    = xi    + 110592;
    float* lutlo = xj    + 110592;        // 2*16*72 = 2304
    float* luthi = lutlo + 2304;
    float* invD  = luthi + 2304;          // 768
    int*   cnt   = (int*)(invD + 768);    // 768
    unsigned* list = (unsigned*)(cnt + 768);          // 768*768 u32
    unsigned char* P = (unsigned char*)(list + N_STK*N_STK);  // 768*768 bytes

    pattern_kernel<<<N_STK, 256, 0, stream>>>(rel, P, invD);
    csc_kernel<<<N_STK, 256, 0, stream>>>(P, list, cnt);
    lut_kernel<<<(2*2*16*INP + 255)/256, 256, 0, stream>>>(hop_w1, hop_b1, lutlo, luthi);
    lstm_kernel<<<(BATCH*N_STK)/4, 256, 0, stream>>>(input_data, lstm_Wih, lstm_Whh,
                                                     lstm_bih, lstm_bhh, seq);

    const float* ein = seq;
    float* eout = eA;
    for (int k = 0; k < 2; k++){
        xixj_kernel<<<(BATCH*N_STK*INP + 255)/256, 256, 0, stream>>>(ein, hop_w1 + k*INP*INP, xi, xj);
        col_kernel<<<N_STK, 256, 0, stream>>>(xi, xj, lutlo + k*16*INP, luthi + k*16*INP,
                                              hop_w2 + k*INP, hop_b2 + k, list, cnt, invD,
                                              ein, eout);
        ein = eout;
        eout = eB;
    }
    head_kernel<<<BATCH*N_STK, 64, 0, stream>>>(seq, ein, fn_w1, fn_b1, fn_w2, fn_b2, out);
}

// Round 3
// 196.518 us; speedup vs baseline: 1.0496x; 1.0390x over previous
//
#include <hip/hip_runtime.h>

#define N_STK 768
#define BATCH 2
#define WIN   32
#define FEAT  4
#define UNITS 32
#define INP   72      // 2U + K
#define PADW  76      // LDS row stride: 19 dwords -> spreads rows across banks

__device__ __forceinline__ float lrelu(float v){ return v > 0.0f ? v : 0.01f*v; }
__device__ __forceinline__ float lanebcast(float v, int l){
    return __int_as_float(__builtin_amdgcn_readlane(__float_as_int(v), l));
}
__device__ __forceinline__ unsigned patof(const float* __restrict__ p){
    float4 a = *reinterpret_cast<const float4*>(p);
    float4 b = *reinterpret_cast<const float4*>(p + 4);
    unsigned m = 0;
    m |= (a.x != 0.0f) ? 1u   : 0u;
    m |= (a.y != 0.0f) ? 2u   : 0u;
    m |= (a.z != 0.0f) ? 4u   : 0u;
    m |= (a.w != 0.0f) ? 8u   : 0u;
    m |= (b.x != 0.0f) ? 16u  : 0u;
    m |= (b.y != 0.0f) ? 32u  : 0u;
    m |= (b.z != 0.0f) ? 64u  : 0u;
    m |= (b.w != 0.0f) ? 128u : 0u;
    return m;
}

// ---------------------------------------------------------------------------
// K1: block j does EVERYTHING independent per j:
//   waves 0,1 : LSTM for sequences (b=0,n=j) and (b=1,n=j)   [no LDS/barriers]
//   wave  2   : D[j] from row j of rel; LUT slice (blocks j<64)
//   wave  3   : CSC column j via wave-level shfl scan (barrier-free)
//   epilogue  : xi0/xj0 rows for (0,j),(1,j) from LDS h-rows
__global__ __launch_bounds__(256) void k1_kernel(const float* __restrict__ rel,
        const float* __restrict__ x, const float* __restrict__ Wih,
        const float* __restrict__ Whh, const float* __restrict__ bih,
        const float* __restrict__ bhh, const float* __restrict__ hop_w1,
        const float* __restrict__ hop_b1,
        float* __restrict__ seq, float* __restrict__ invD, int* __restrict__ cnt,
        unsigned* __restrict__ list, float* __restrict__ lutlo, float* __restrict__ luthi,
        float* __restrict__ xi0, float* __restrict__ xj0){
    int j = blockIdx.x, tid = threadIdx.x;
    int wv = tid >> 6, lane = tid & 63;
    __shared__ float hrow[2][UNITS];

    if (wv < 2){
        // ---- LSTM, one sequence per wave ----
        int b = wv;
        int r0 = lane, r1 = 64 + lane;
        bool low = (lane < 32);
        float4 wi0 = *reinterpret_cast<const float4*>(Wih + r0*FEAT);
        float4 wi1 = *reinterpret_cast<const float4*>(Wih + r1*FEAT);
        float bb0 = bih[r0] + bhh[r0];
        float bb1 = bih[r1] + bhh[r1];
        float4 W0[8], W1[8];
        #pragma unroll
        for (int q = 0; q < 8; q++){
            W0[q] = *reinterpret_cast<const float4*>(Whh + r0*UNITS + q*4);
            W1[q] = *reinterpret_cast<const float4*>(Whh + r1*UNITS + q*4);
        }
        float4 xv = make_float4(0.f, 0.f, 0.f, 0.f);
        if (low) xv = *reinterpret_cast<const float4*>(x + ((size_t)(b*WIN + lane)*N_STK + j)*FEAT);
        float hreg = 0.0f, c = 0.0f;
        #pragma unroll 1
        for (int t = 0; t < WIN; t++){
            float xb0 = lanebcast(xv.x, t), xb1 = lanebcast(xv.y, t);
            float xb2 = lanebcast(xv.z, t), xb3 = lanebcast(xv.w, t);
            float z0a = bb0 + wi0.x*xb0 + wi0.z*xb2;
            float z0b =       wi0.y*xb1 + wi0.w*xb3;
            float z1a = bb1 + wi1.x*xb0 + wi1.z*xb2;
            float z1b =       wi1.y*xb1 + wi1.w*xb3;
            #pragma unroll
            for (int q = 0; q < 8; q++){
                float h0 = lanebcast(hreg, 32 + q*4 + 0);
                float h1 = lanebcast(hreg, 32 + q*4 + 1);
                float h2 = lanebcast(hreg, 32 + q*4 + 2);
                float h3 = lanebcast(hreg, 32 + q*4 + 3);
                z0a += W0[q].x*h0; z0b += W0[q].y*h1;
                z0a += W0[q].z*h2; z0b += W0[q].w*h3;
                z1a += W1[q].x*h0; z1b += W1[q].y*h1;
                z1a += W1[q].z*h2; z1b += W1[q].w*h3;
            }
            float z0 = z0a + z0b, z1 = z1a + z1b;
            float e0 = __expf(-z0);
            float s0 = 1.0f/(1.0f + e0);                 // sig(i) / sig(f)
            float sc = low ? -2.0f : -1.0f;
            float e1 = __expf(sc*z1);
            float rr = 1.0f/(1.0f + e1);
            float act = low ? (1.0f - e1)*rr : rr;       // tanh(g) / sig(o)
            float pa = s0*act;                            // lower: sig(i)*tanh(g)
            float po = __shfl_xor(pa, 32);
            c = s0*c + po;                                // upper: sig(f)*c + i*g
            float e2 = __expf(-2.0f*c);
            float th = (1.0f - e2)/(1.0f + e2);           // tanh(c)
            hreg = act*th;                                // upper: sig(o)*tanh(c)
        }
        if (!low){
            hrow[b][lane - 32] = hreg;
            seq[((size_t)b*N_STK + j)*UNITS + (lane - 32)] = hreg;
        }
    } else if (wv == 2){
        // ---- degree of row j ----
        int local = 0;
        for (int jj = lane; jj < N_STK; jj += 64){
            unsigned p = patof(rel + ((size_t)j*N_STK + jj)*8);
            local += p ? 1 : 0;
        }
        #pragma unroll
        for (int d = 32; d; d >>= 1) local += __shfl_xor(local, d);
        if (lane == 0) invD[j] = 1.0f/(float)local;
        // ---- LUT slice: block j<64 covers (k=j>>5, half=(j>>4)&1, m=j&15) ----
        if (j < 64){
            int m = j & 15, half = (j >> 4) & 1, k = j >> 5;
            const float* W = hop_w1 + (size_t)k*INP*INP;
            int base = 2*UNITS + (half ? 4 : 0);
            for (int p = lane; p < INP; p += 64){
                float acc = half ? 0.0f : hop_b1[k*INP + p];
                #pragma unroll
                for (int q = 0; q < 4; q++)
                    if ((m >> q) & 1) acc += W[(base + q)*INP + p];
                (half ? luthi : lutlo)[(k*16 + m)*INP + p] = acc;
            }
        }
    } else {
        // ---- CSC column j, wave-level scan (no barriers) ----
        unsigned char pv[12];
        int c = 0;
        #pragma unroll
        for (int r = 0; r < 12; r++){
            int i = lane*12 + r;
            unsigned p = patof(rel + ((size_t)i*N_STK + j)*8);
            pv[r] = (unsigned char)p;
            c += p ? 1 : 0;
        }
        int sc = c;
        #pragma unroll
        for (int off = 1; off < 64; off <<= 1){
            int v = __shfl_up(sc, off);
            if (lane >= off) sc += v;
        }
        int slot = sc - c;
        #pragma unroll
        for (int r = 0; r < 12; r++)
            if (pv[r]) list[(size_t)j*N_STK + (slot++)] = (unsigned)(((lane*12 + r) << 8) | pv[r]);
        int total = __shfl(sc, 63);
        if (lane == 0) cnt[j] = total;
    }
    __syncthreads();
    // ---- xi0/xj0 for rows (0,j),(1,j), hop k=0 weights ----
    if (tid < 2*INP){
        int b = tid/INP, p = tid%INP;
        float si = 0.0f, sj = 0.0f;
        #pragma unroll
        for (int u = 0; u < UNITS; u++){
            float ev = hrow[b][u];
            si += ev * hop_w1[u*INP + p];
            sj += ev * hop_w1[(UNITS + u)*INP + p];
        }
        size_t o = ((size_t)b*N_STK + j)*INP + p;
        xi0[o] = si; xj0[o] = sj;
    }
}

// ---------------------------------------------------------------------------
// col kernel: one block per column j; both batches.
//   s[b,j] = sum over nonzero (i,pat) of lrelu(dot(lrelu(xi_i+xj_j+lut_pat),w2)+b2)/D_i
// MODE 0: eout = ein*s, then xi_next/xj_next for row j with W1next.
// MODE 1: FC head on [seq_row, ein_row*s] -> outp[b*N+j]. (e never hits memory)
template<int MODE>
__global__ __launch_bounds__(256) void col_kernel(const float* __restrict__ xi,
        const float* __restrict__ xj,
        const float* __restrict__ lutlo_k, const float* __restrict__ luthi_k,
        const float* __restrict__ w2, const float* __restrict__ b2,
        const unsigned* __restrict__ list, const int* __restrict__ cnt,
        const float* __restrict__ invD,
        const float* __restrict__ ein, float* __restrict__ eout,
        const float* __restrict__ W1next, float* __restrict__ xi_next, float* __restrict__ xj_next,
        const float* __restrict__ seqg, const float* __restrict__ fw1,
        const float* __restrict__ fb1, const float* __restrict__ fw2,
        const float* __restrict__ fb2, float* __restrict__ outp){
    int j = blockIdx.x, tid = threadIdx.x;
    int cn = cnt[j];
    __shared__ float xjlo_sh[2][16][PADW];   // xj[b,j,:] + lutlo[m,:]
    __shared__ float hi_sh[16][PADW];
    __shared__ float red0[4], red1[4];
    __shared__ float sval[2];
    __shared__ float ep_sh[2][64];           // MODE0: e-row (first 32); MODE1: comb
    for (int idx = tid; idx < 16*INP; idx += 256){
        int m = idx / INP, p = idx % INP;
        float lo = lutlo_k[m*INP + p];
        xjlo_sh[0][m][p] = lo + xj[((size_t)0*N_STK + j)*INP + p];
        xjlo_sh[1][m][p] = lo + xj[((size_t)1*N_STK + j)*INP + p];
        hi_sh[m][p] = luthi_k[m*INP + p];
    }
    float4 w2r[18];
    #pragma unroll
    for (int q = 0; q < 18; q++) w2r[q] = *reinterpret_cast<const float4*>(w2 + q*4);
    float b2v = b2[0];
    __syncthreads();

    float acc0 = 0.0f, acc1 = 0.0f;
    for (int p = tid; p < cn; p += 256){
        unsigned ent = list[(size_t)j*N_STK + p];
        int i = (int)(ent >> 8);
        int mlo = (int)(ent & 15u), mhi = (int)((ent >> 4) & 15u);
        float id = invD[i];
        const float* xi0p = xi + ((size_t)0*N_STK + i)*INP;
        const float* xi1p = xi + ((size_t)1*N_STK + i)*INP;
        const float* jl0 = &xjlo_sh[0][mlo][0];
        const float* jl1 = &xjlo_sh[1][mlo][0];
        const float* hh  = &hi_sh[mhi][0];
        float4 a0 = make_float4(0.f,0.f,0.f,0.f);
        float4 a1 = make_float4(0.f,0.f,0.f,0.f);
        #pragma unroll
        for (int q = 0; q < 18; q++){
            float4 h4 = *reinterpret_cast<const float4*>(hh + q*4);
            float4 x0 = *reinterpret_cast<const float4*>(xi0p + q*4);
            float4 j0 = *reinterpret_cast<const float4*>(jl0 + q*4);
            float4 x1 = *reinterpret_cast<const float4*>(xi1p + q*4);
            float4 j1 = *reinterpret_cast<const float4*>(jl1 + q*4);
            float4 w  = w2r[q];
            a0.x += lrelu(x0.x + j0.x + h4.x)*w.x;
            a0.y += lrelu(x0.y + j0.y + h4.y)*w.y;
            a0.z += lrelu(x0.z + j0.z + h4.z)*w.z;
            a0.w += lrelu(x0.w + j0.w + h4.w)*w.w;
            a1.x += lrelu(x1.x + j1.x + h4.x)*w.x;
            a1.y += lrelu(x1.y + j1.y + h4.y)*w.y;
            a1.z += lrelu(x1.z + j1.z + h4.z)*w.z;
            a1.w += lrelu(x1.w + j1.w + h4.w)*w.w;
        }
        acc0 += lrelu(a0.x + a0.y + a0.z + a0.w + b2v)*id;
        acc1 += lrelu(a1.x + a1.y + a1.z + a1.w + b2v)*id;
    }
    #pragma unroll
    for (int d = 1; d < 64; d <<= 1){
        acc0 += __shfl_xor(acc0, d);
        acc1 += __shfl_xor(acc1, d);
    }
    if ((tid & 63) == 0){ red0[tid >> 6] = acc0; red1[tid >> 6] = acc1; }
    __syncthreads();
    if (tid == 0){
        sval[0] = red0[0] + red0[1] + red0[2] + red0[3];
        sval[1] = red1[0] + red1[1] + red1[2] + red1[3];
    }
    __syncthreads();

    if (tid < 64){
        int b = tid >> 5, u = tid & 31;
        size_t o = ((size_t)b*N_STK + j)*UNITS + u;
        float ev = ein[o]*sval[b];
        if (MODE == 0){
            ep_sh[b][u] = ev;
            eout[o] = ev;
        } else {
            ep_sh[b][32 + u] = ev;
            ep_sh[b][u] = seqg[o];
        }
    }
    __syncthreads();
    if (MODE == 0){
        // xi/xj for the NEXT hop, row j
        if (tid < 2*INP){
            int b = tid/INP, p = tid%INP;
            float si = 0.0f, sj = 0.0f;
            #pragma unroll
            for (int u = 0; u < UNITS; u++){
                float ev = ep_sh[b][u];
                si += ev * W1next[u*INP + p];
                sj += ev * W1next[(UNITS + u)*INP + p];
            }
            size_t o = ((size_t)b*N_STK + j)*INP + p;
            xi_next[o] = si; xj_next[o] = sj;
        }
    } else {
        // FC head: thread t<128, b = t>>6, u = t&63
        if (tid < 128){
            int b = tid >> 6, u = tid & 63;
            float acc = fb1[u];
            #pragma unroll 8
            for (int d = 0; d < 64; d++) acc += ep_sh[b][d]*fw1[d*64 + u];
            float prod = lrelu(acc)*fw2[u];
            prod += __shfl_xor(prod, 32);
            prod += __shfl_xor(prod, 16);
            prod += __shfl_xor(prod, 8);
            prod += __shfl_xor(prod, 4);
            prod += __shfl_xor(prod, 2);
            prod += __shfl_xor(prod, 1);
            if (u == 0) outp[b*N_STK + j] = lrelu(prod + fb2[0]);
        }
    }
}

// ---------------------------------------------------------------------------
extern "C" void kernel_launch(void* const* d_in, const int* in_sizes, int n_in,
                              void* d_out, int out_size, void* d_ws, size_t ws_size,
                              hipStream_t stream){
    const float* input_data = (const float*)d_in[0];
    const float* rel        = (const float*)d_in[1];
    const float* lstm_Wih   = (const float*)d_in[2];
    const float* lstm_Whh   = (const float*)d_in[3];
    const float* lstm_bih   = (const float*)d_in[4];
    const float* lstm_bhh   = (const float*)d_in[5];
    const float* hop_w1     = (const float*)d_in[6];
    const float* hop_b1     = (const float*)d_in[7];
    const float* hop_w2     = (const float*)d_in[8];
    const float* hop_b2     = (const float*)d_in[9];
    const float* fn_w1      = (const float*)d_in[10];
    const float* fn_b1      = (const float*)d_in[11];
    const float* fn_w2      = (const float*)d_in[12];
    const float* fn_b2      = (const float*)d_in[13];
    float* out = (float*)d_out;

    // workspace layout (floats; all chunks 16B-aligned)
    float* ws    = (float*)d_ws;
    float* seq   = ws;                    // 49152
    float* eA    = seq   + 49152;         // 49152
    float* xi0   = eA    + 49152;         // 110592
    float* xj0   = xi0   + 110592;
    float* xi1   = xj0   + 110592;
    float* xj1   = xi1   + 110592;
    float* lutlo = xj1   + 110592;        // 2*16*72 = 2304
    float* luthi = lutlo + 2304;
    float* invD  = luthi + 2304;          // 768
    int*   cnt   = (int*)(invD + 768);    // 768
    unsigned* list = (unsigned*)(cnt + 768);  // 768*768 u32

    k1_kernel<<<N_STK, 256, 0, stream>>>(rel, input_data, lstm_Wih, lstm_Whh,
            lstm_bih, lstm_bhh, hop_w1, hop_b1,
            seq, invD, cnt, list, lutlo, luthi, xi0, xj0);

    col_kernel<0><<<N_STK, 256, 0, stream>>>(xi0, xj0, lutlo, luthi,
            hop_w2, hop_b2, list, cnt, invD,
            seq, eA, hop_w1 + INP*INP, xi1, xj1,
            nullptr, nullptr, nullptr, nullptr, nullptr, nullptr);

    col_kernel<1><<<N_STK, 256, 0, stream>>>(xi1, xj1, lutlo + 16*INP, luthi + 16*INP,
            hop_w2 + INP, hop_b2 + 1, list, cnt, invD,
            eA, nullptr, nullptr, nullptr, nullptr,
            seq, fn_w1, fn_b1, fn_w2, fn_b2, out);
}

// Round 4
// 176.857 us; speedup vs baseline: 1.1662x; 1.1112x over previous
//
#include <hip/hip_runtime.h>

#define N_STK 768
#define BATCH 2
#define WIN   32
#define FEAT  4
#define UNITS 32
#define INP   72      // 2U + K
#define CHUNK 64      // entries staged per iteration in col_kernel

__device__ __forceinline__ float lrelu(float v){ return v > 0.0f ? v : 0.01f*v; }
__device__ __forceinline__ float lanebcast(float v, int l){
    return __int_as_float(__builtin_amdgcn_readlane(__float_as_int(v), l));
}
__device__ __forceinline__ unsigned patof(const float* __restrict__ p){
    float4 a = *reinterpret_cast<const float4*>(p);
    float4 b = *reinterpret_cast<const float4*>(p + 4);
    unsigned m = 0;
    m |= (a.x != 0.0f) ? 1u   : 0u;
    m |= (a.y != 0.0f) ? 2u   : 0u;
    m |= (a.z != 0.0f) ? 4u   : 0u;
    m |= (a.w != 0.0f) ? 8u   : 0u;
    m |= (b.x != 0.0f) ? 16u  : 0u;
    m |= (b.y != 0.0f) ? 32u  : 0u;
    m |= (b.z != 0.0f) ? 64u  : 0u;
    m |= (b.w != 0.0f) ? 128u : 0u;
    return m;
}

// ---------------------------------------------------------------------------
// K1: block j does EVERYTHING independent per j:
//   waves 0,1 : LSTM for sequences (b=0,n=j) and (b=1,n=j)   [no LDS/barriers]
//   wave  2   : D[j] from row j of rel; LUT slice (blocks j<64)
//   wave  3   : CSC column j via wave-level shfl scan (barrier-free)
//   epilogue  : xi0/xj0 rows for (0,j),(1,j) from LDS h-rows
__global__ __launch_bounds__(256) void k1_kernel(const float* __restrict__ rel,
        const float* __restrict__ x, const float* __restrict__ Wih,
        const float* __restrict__ Whh, const float* __restrict__ bih,
        const float* __restrict__ bhh, const float* __restrict__ hop_w1,
        const float* __restrict__ hop_b1,
        float* __restrict__ seq, float* __restrict__ invD, int* __restrict__ cnt,
        unsigned* __restrict__ list, float* __restrict__ lutlo, float* __restrict__ luthi,
        float* __restrict__ xi0, float* __restrict__ xj0){
    int j = blockIdx.x, tid = threadIdx.x;
    int wv = tid >> 6, lane = tid & 63;
    __shared__ float hrow[2][UNITS];

    if (wv < 2){
        // ---- LSTM, one sequence per wave ----
        int b = wv;
        int r0 = lane, r1 = 64 + lane;
        bool low = (lane < 32);
        float4 wi0 = *reinterpret_cast<const float4*>(Wih + r0*FEAT);
        float4 wi1 = *reinterpret_cast<const float4*>(Wih + r1*FEAT);
        float bb0 = bih[r0] + bhh[r0];
        float bb1 = bih[r1] + bhh[r1];
        float4 W0[8], W1[8];
        #pragma unroll
        for (int q = 0; q < 8; q++){
            W0[q] = *reinterpret_cast<const float4*>(Whh + r0*UNITS + q*4);
            W1[q] = *reinterpret_cast<const float4*>(Whh + r1*UNITS + q*4);
        }
        float4 xv = make_float4(0.f, 0.f, 0.f, 0.f);
        if (low) xv = *reinterpret_cast<const float4*>(x + ((size_t)(b*WIN + lane)*N_STK + j)*FEAT);
        float hreg = 0.0f, c = 0.0f;
        #pragma unroll 1
        for (int t = 0; t < WIN; t++){
            float xb0 = lanebcast(xv.x, t), xb1 = lanebcast(xv.y, t);
            float xb2 = lanebcast(xv.z, t), xb3 = lanebcast(xv.w, t);
            float z0a = bb0 + wi0.x*xb0 + wi0.z*xb2;
            float z0b =       wi0.y*xb1 + wi0.w*xb3;
            float z1a = bb1 + wi1.x*xb0 + wi1.z*xb2;
            float z1b =       wi1.y*xb1 + wi1.w*xb3;
            #pragma unroll
            for (int q = 0; q < 8; q++){
                float h0 = lanebcast(hreg, 32 + q*4 + 0);
                float h1 = lanebcast(hreg, 32 + q*4 + 1);
                float h2 = lanebcast(hreg, 32 + q*4 + 2);
                float h3 = lanebcast(hreg, 32 + q*4 + 3);
                z0a += W0[q].x*h0; z0b += W0[q].y*h1;
                z0a += W0[q].z*h2; z0b += W0[q].w*h3;
                z1a += W1[q].x*h0; z1b += W1[q].y*h1;
                z1a += W1[q].z*h2; z1b += W1[q].w*h3;
            }
            float z0 = z0a + z0b, z1 = z1a + z1b;
            float e0 = __expf(-z0);
            float s0 = 1.0f/(1.0f + e0);                 // sig(i) / sig(f)
            float sc = low ? -2.0f : -1.0f;
            float e1 = __expf(sc*z1);
            float rr = 1.0f/(1.0f + e1);
            float act = low ? (1.0f - e1)*rr : rr;       // tanh(g) / sig(o)
            float pa = s0*act;                            // lower: sig(i)*tanh(g)
            float po = __shfl_xor(pa, 32);
            c = s0*c + po;                                // upper: sig(f)*c + i*g
            float e2 = __expf(-2.0f*c);
            float th = (1.0f - e2)/(1.0f + e2);           // tanh(c)
            hreg = act*th;                                // upper: sig(o)*tanh(c)
        }
        if (!low){
            hrow[b][lane - 32] = hreg;
            seq[((size_t)b*N_STK + j)*UNITS + (lane - 32)] = hreg;
        }
    } else if (wv == 2){
        // ---- degree of row j ----
        int local = 0;
        for (int jj = lane; jj < N_STK; jj += 64){
            unsigned p = patof(rel + ((size_t)j*N_STK + jj)*8);
            local += p ? 1 : 0;
        }
        #pragma unroll
        for (int d = 32; d; d >>= 1) local += __shfl_xor(local, d);
        if (lane == 0) invD[j] = 1.0f/(float)local;
        // ---- LUT slice: block j<64 covers (k=j>>5, half=(j>>4)&1, m=j&15) ----
        if (j < 64){
            int m = j & 15, half = (j >> 4) & 1, k = j >> 5;
            const float* W = hop_w1 + (size_t)k*INP*INP;
            int base = 2*UNITS + (half ? 4 : 0);
            for (int p = lane; p < INP; p += 64){
                float acc = half ? 0.0f : hop_b1[k*INP + p];
                #pragma unroll
                for (int q = 0; q < 4; q++)
                    if ((m >> q) & 1) acc += W[(base + q)*INP + p];
                (half ? luthi : lutlo)[(k*16 + m)*INP + p] = acc;
            }
        }
    } else {
        // ---- CSC column j, wave-level scan (no barriers) ----
        unsigned char pv[12];
        int c = 0;
        #pragma unroll
        for (int r = 0; r < 12; r++){
            int i = lane*12 + r;
            unsigned p = patof(rel + ((size_t)i*N_STK + j)*8);
            pv[r] = (unsigned char)p;
            c += p ? 1 : 0;
        }
        int sc = c;
        #pragma unroll
        for (int off = 1; off < 64; off <<= 1){
            int v = __shfl_up(sc, off);
            if (lane >= off) sc += v;
        }
        int slot = sc - c;
        #pragma unroll
        for (int r = 0; r < 12; r++)
            if (pv[r]) list[(size_t)j*N_STK + (slot++)] = (unsigned)(((lane*12 + r) << 8) | pv[r]);
        int total = __shfl(sc, 63);
        if (lane == 0) cnt[j] = total;
    }
    __syncthreads();
    // ---- xi0/xj0 for rows (0,j),(1,j), hop k=0 weights ----
    if (tid < 2*INP){
        int b = tid/INP, p = tid%INP;
        float si = 0.0f, sj = 0.0f;
        #pragma unroll
        for (int u = 0; u < UNITS; u++){
            float ev = hrow[b][u];
            si += ev * hop_w1[u*INP + p];
            sj += ev * hop_w1[(UNITS + u)*INP + p];
        }
        size_t o = ((size_t)b*N_STK + j)*INP + p;
        xi0[o] = si; xj0[o] = sj;
    }
}

// ---------------------------------------------------------------------------
// col kernel v2: one block per column j; both batches.
//   s[b,j] = sum over nonzero (i,pat) of lrelu(dot(lrelu(xi_i+xj_j+lut_pat),w2)+b2)/D_i
// Entries processed in chunks of 64. xi rows for the chunk are staged into LDS
// with within-row-contiguous (coalesced) loads; compute threads map
// (entry, batch, half) -> tid = e*4 + b*2 + hf, each doing a 9-step half-dot
// purely from LDS, halves combined via shfl_xor(1).
// MODE 0: eout = ein*s, then xi_next/xj_next for row j with W1next.
// MODE 1: FC head on [seq_row, ein_row*s] -> outp[b*N+j]. (e never hits memory)
template<int MODE>
__global__ __launch_bounds__(256) void col_kernel(const float* __restrict__ xi,
        const float* __restrict__ xj,
        const float* __restrict__ lutlo_k, const float* __restrict__ luthi_k,
        const float* __restrict__ w2, const float* __restrict__ b2,
        const unsigned* __restrict__ list, const int* __restrict__ cnt,
        const float* __restrict__ invD,
        const float* __restrict__ ein, float* __restrict__ eout,
        const float* __restrict__ W1next, float* __restrict__ xi_next, float* __restrict__ xj_next,
        const float* __restrict__ seqg, const float* __restrict__ fw1,
        const float* __restrict__ fb1, const float* __restrict__ fw2,
        const float* __restrict__ fb2, float* __restrict__ outp){
    int j = blockIdx.x, tid = threadIdx.x;
    int cn = cnt[j];
    __shared__ float xi_sh[2][CHUNK*INP];    // 36864 B: staged xi rows (stride 72 dw)
    __shared__ float xjlo_sh[2][16*INP];     //  9216 B: xj[b,j,:] + lutlo[m,:]
    __shared__ float hi_sh[16*INP];          //  4608 B
    __shared__ float red[4][2];
    __shared__ float sval[2];
    __shared__ float ep_sh[2][64];
    for (int idx = tid; idx < 16*INP; idx += 256){
        float lo = lutlo_k[idx];
        xjlo_sh[0][idx] = lo + xj[((size_t)0*N_STK + j)*INP + (idx % INP)];
        xjlo_sh[1][idx] = lo + xj[((size_t)1*N_STK + j)*INP + (idx % INP)];
        hi_sh[idx] = luthi_k[idx];
    }
    int e  = tid >> 2;          // entry slot 0..63
    int bb = (tid >> 1) & 1;    // batch
    int hf = tid & 1;           // half of the 72-dot
    float4 w2h[9];
    #pragma unroll
    for (int q = 0; q < 9; q++) w2h[q] = *reinterpret_cast<const float4*>(w2 + hf*36 + q*4);
    float b2v = b2[0];
    float accb = 0.0f;          // partial s for batch bb (only hf==0 lanes accumulate)

    for (int base = 0; base < cn; base += CHUNK){
        __syncthreads();        // xi_sh readers from previous chunk done
        // ---- stage xi rows for entries [base, base+CHUNK) ----
        for (int u = tid; u < CHUNK*36; u += 256){
            int eu = u / 36;
            if (base + eu < cn){
                int r = u - eu*36;
                int sb = r / 18, q = r - sb*18;
                unsigned ent = list[(size_t)j*N_STK + base + eu];
                int i = (int)(ent >> 8);
                *reinterpret_cast<float4*>(&xi_sh[sb][eu*INP + q*4]) =
                    *reinterpret_cast<const float4*>(xi + ((size_t)sb*N_STK + i)*INP + q*4);
            }
        }
        __syncthreads();
        // ---- compute ----
        bool alive = (base + e < cn);
        unsigned ent = alive ? list[(size_t)j*N_STK + base + e] : 0u;
        int i = (int)(ent >> 8);
        int mlo = (int)(ent & 15u), mhi = (int)((ent >> 4) & 15u);
        const float* xr = &xi_sh[bb][e*INP + hf*36];
        const float* jr = &xjlo_sh[bb][mlo*INP + hf*36];
        const float* hr = &hi_sh[mhi*INP + hf*36];
        float4 a = make_float4(0.f, 0.f, 0.f, 0.f);
        #pragma unroll
        for (int q = 0; q < 9; q++){
            float4 xv = *reinterpret_cast<const float4*>(xr + q*4);
            float4 jv = *reinterpret_cast<const float4*>(jr + q*4);
            float4 hv = *reinterpret_cast<const float4*>(hr + q*4);
            float4 w  = w2h[q];
            a.x += lrelu(xv.x + jv.x + hv.x)*w.x;
            a.y += lrelu(xv.y + jv.y + hv.y)*w.y;
            a.z += lrelu(xv.z + jv.z + hv.z)*w.z;
            a.w += lrelu(xv.w + jv.w + hv.w)*w.w;
        }
        float dot = a.x + a.y + a.z + a.w;
        dot += __shfl_xor(dot, 1);                 // combine halves
        if (alive && hf == 0) accb += lrelu(dot + b2v)*invD[i];
    }
    // reduce over entry slots within wave (lanes 0 mod 4 = batch0, 2 mod 4 = batch1)
    #pragma unroll
    for (int d = 4; d < 64; d <<= 1) accb += __shfl_xor(accb, d);
    int lw = tid & 63, w = tid >> 6;
    if (lw == 0) red[w][0] = accb;
    if (lw == 2) red[w][1] = accb;
    __syncthreads();
    if (tid < 2) sval[tid] = red[0][tid] + red[1][tid] + red[2][tid] + red[3][tid];
    __syncthreads();

    if (tid < 64){
        int b = tid >> 5, u = tid & 31;
        size_t o = ((size_t)b*N_STK + j)*UNITS + u;
        float ev = ein[o]*sval[b];
        if (MODE == 0){
            ep_sh[b][u] = ev;
            eout[o] = ev;
        } else {
            ep_sh[b][32 + u] = ev;
            ep_sh[b][u] = seqg[o];
        }
    }
    __syncthreads();
    if (MODE == 0){
        // xi/xj for the NEXT hop, row j
        if (tid < 2*INP){
            int b = tid/INP, p = tid%INP;
            float si = 0.0f, sj = 0.0f;
            #pragma unroll
            for (int u = 0; u < UNITS; u++){
                float ev = ep_sh[b][u];
                si += ev * W1next[u*INP + p];
                sj += ev * W1next[(UNITS + u)*INP + p];
            }
            size_t o = ((size_t)b*N_STK + j)*INP + p;
            xi_next[o] = si; xj_next[o] = sj;
        }
    } else {
        // FC head: thread t<128, b = t>>6, u = t&63
        if (tid < 128){
            int b = tid >> 6, u = tid & 63;
            float acc = fb1[u];
            #pragma unroll 8
            for (int d = 0; d < 64; d++) acc += ep_sh[b][d]*fw1[d*64 + u];
            float prod = lrelu(acc)*fw2[u];
            prod += __shfl_xor(prod, 32);
            prod += __shfl_xor(prod, 16);
            prod += __shfl_xor(prod, 8);
            prod += __shfl_xor(prod, 4);
            prod += __shfl_xor(prod, 2);
            prod += __shfl_xor(prod, 1);
            if (u == 0) outp[b*N_STK + j] = lrelu(prod + fb2[0]);
        }
    }
}

// ---------------------------------------------------------------------------
extern "C" void kernel_launch(void* const* d_in, const int* in_sizes, int n_in,
                              void* d_out, int out_size, void* d_ws, size_t ws_size,
                              hipStream_t stream){
    const float* input_data = (const float*)d_in[0];
    const float* rel        = (const float*)d_in[1];
    const float* lstm_Wih   = (const float*)d_in[2];
    const float* lstm_Whh   = (const float*)d_in[3];
    const float* lstm_bih   = (const float*)d_in[4];
    const float* lstm_bhh   = (const float*)d_in[5];
    const float* hop_w1     = (const float*)d_in[6];
    const float* hop_b1     = (const float*)d_in[7];
    const float* hop_w2     = (const float*)d_in[8];
    const float* hop_b2     = (const float*)d_in[9];
    const float* fn_w1      = (const float*)d_in[10];
    const float* fn_b1      = (const float*)d_in[11];
    const float* fn_w2      = (const float*)d_in[12];
    const float* fn_b2      = (const float*)d_in[13];
    float* out = (float*)d_out;

    // workspace layout (floats; all chunks 16B-aligned)
    float* ws    = (float*)d_ws;
    float* seq   = ws;                    // 49152
    float* eA    = seq   + 49152;         // 49152
    float* xi0   = eA    + 49152;         // 110592
    float* xj0   = xi0   + 110592;
    float* xi1   = xj0   + 110592;
    float* xj1   = xi1   + 110592;
    float* lutlo = xj1   + 110592;        // 2*16*72 = 2304
    float* luthi = lutlo + 2304;
    float* invD  = luthi + 2304;          // 768
    int*   cnt   = (int*)(invD + 768);    // 768
    unsigned* list = (unsigned*)(cnt + 768);  // 768*768 u32

    k1_kernel<<<N_STK, 256, 0, stream>>>(rel, input_data, lstm_Wih, lstm_Whh,
            lstm_bih, lstm_bhh, hop_w1, hop_b1,
            seq, invD, cnt, list, lutlo, luthi, xi0, xj0);

    col_kernel<0><<<N_STK, 256, 0, stream>>>(xi0, xj0, lutlo, luthi,
            hop_w2, hop_b2, list, cnt, invD,
            seq, eA, hop_w1 + INP*INP, xi1, xj1,
            nullptr, nullptr, nullptr, nullptr, nullptr, nullptr);

    col_kernel<1><<<N_STK, 256, 0, stream>>>(xi1, xj1, lutlo + 16*INP, luthi + 16*INP,
            hop_w2 + INP, hop_b2 + 1, list, cnt, invD,
            eA, nullptr, nullptr, nullptr, nullptr,
            seq, fn_w1, fn_b1, fn_w2, fn_b2, out);
}

// Round 5
// 168.200 us; speedup vs baseline: 1.2263x; 1.0515x over previous
//
#include <hip/hip_runtime.h>

#define N_STK 768
#define BATCH 2
#define WIN   32
#define FEAT  4
#define UNITS 32
#define INP   72      // 2U + K
#define CHUNK 64      // entries per double-buffered chunk in col_kernel
#define LROW  76      // padded LDS row stride (dwords): 16B-aligned, ~2-way banks
#define NSLC  19      // 16B slices per padded row (slice 18 = pad, dummy load)

__device__ __forceinline__ float lrelu(float v){ return v > 0.0f ? v : 0.01f*v; }
__device__ __forceinline__ float lanebcast(float v, int l){
    return __int_as_float(__builtin_amdgcn_readlane(__float_as_int(v), l));
}
__device__ __forceinline__ unsigned patof(const float* __restrict__ p){
    float4 a = *reinterpret_cast<const float4*>(p);
    float4 b = *reinterpret_cast<const float4*>(p + 4);
    unsigned m = 0;
    m |= (a.x != 0.0f) ? 1u   : 0u;
    m |= (a.y != 0.0f) ? 2u   : 0u;
    m |= (a.z != 0.0f) ? 4u   : 0u;
    m |= (a.w != 0.0f) ? 8u   : 0u;
    m |= (b.x != 0.0f) ? 16u  : 0u;
    m |= (b.y != 0.0f) ? 32u  : 0u;
    m |= (b.z != 0.0f) ? 64u  : 0u;
    m |= (b.w != 0.0f) ? 128u : 0u;
    return m;
}
// async 16B global -> LDS (direct, no VGPR round-trip). Dest must be
// wave-uniform base + lane*16 (guaranteed by our u-slot mapping).
__device__ __forceinline__ void async_cp16(const float* g, float* l){
    __builtin_amdgcn_global_load_lds(
        (const __attribute__((address_space(1))) unsigned int*)g,
        (__attribute__((address_space(3))) unsigned int*)l,
        16, 0, 0);
}

// ---------------------------------------------------------------------------
// K1: block j does EVERYTHING independent per j (unchanged from R4):
//   waves 0,1 : LSTM for sequences (b=0,n=j) and (b=1,n=j)
//   wave  2   : D[j] from row j of rel; LUT slice (blocks j<64)
//   wave  3   : CSC column j via wave-level shfl scan
//   epilogue  : xi0/xj0 rows for (0,j),(1,j)
__global__ __launch_bounds__(256) void k1_kernel(const float* __restrict__ rel,
        const float* __restrict__ x, const float* __restrict__ Wih,
        const float* __restrict__ Whh, const float* __restrict__ bih,
        const float* __restrict__ bhh, const float* __restrict__ hop_w1,
        const float* __restrict__ hop_b1,
        float* __restrict__ seq, float* __restrict__ invD, int* __restrict__ cnt,
        unsigned* __restrict__ list, float* __restrict__ lutlo, float* __restrict__ luthi,
        float* __restrict__ xi0, float* __restrict__ xj0){
    int j = blockIdx.x, tid = threadIdx.x;
    int wv = tid >> 6, lane = tid & 63;
    __shared__ float hrow[2][UNITS];

    if (wv < 2){
        int b = wv;
        int r0 = lane, r1 = 64 + lane;
        bool low = (lane < 32);
        float4 wi0 = *reinterpret_cast<const float4*>(Wih + r0*FEAT);
        float4 wi1 = *reinterpret_cast<const float4*>(Wih + r1*FEAT);
        float bb0 = bih[r0] + bhh[r0];
        float bb1 = bih[r1] + bhh[r1];
        float4 W0[8], W1[8];
        #pragma unroll
        for (int q = 0; q < 8; q++){
            W0[q] = *reinterpret_cast<const float4*>(Whh + r0*UNITS + q*4);
            W1[q] = *reinterpret_cast<const float4*>(Whh + r1*UNITS + q*4);
        }
        float4 xv = make_float4(0.f, 0.f, 0.f, 0.f);
        if (low) xv = *reinterpret_cast<const float4*>(x + ((size_t)(b*WIN + lane)*N_STK + j)*FEAT);
        float hreg = 0.0f, c = 0.0f;
        #pragma unroll 1
        for (int t = 0; t < WIN; t++){
            float xb0 = lanebcast(xv.x, t), xb1 = lanebcast(xv.y, t);
            float xb2 = lanebcast(xv.z, t), xb3 = lanebcast(xv.w, t);
            float z0a = bb0 + wi0.x*xb0 + wi0.z*xb2;
            float z0b =       wi0.y*xb1 + wi0.w*xb3;
            float z1a = bb1 + wi1.x*xb0 + wi1.z*xb2;
            float z1b =       wi1.y*xb1 + wi1.w*xb3;
            #pragma unroll
            for (int q = 0; q < 8; q++){
                float h0 = lanebcast(hreg, 32 + q*4 + 0);
                float h1 = lanebcast(hreg, 32 + q*4 + 1);
                float h2 = lanebcast(hreg, 32 + q*4 + 2);
                float h3 = lanebcast(hreg, 32 + q*4 + 3);
                z0a += W0[q].x*h0; z0b += W0[q].y*h1;
                z0a += W0[q].z*h2; z0b += W0[q].w*h3;
                z1a += W1[q].x*h0; z1b += W1[q].y*h1;
                z1a += W1[q].z*h2; z1b += W1[q].w*h3;
            }
            float z0 = z0a + z0b, z1 = z1a + z1b;
            float e0 = __expf(-z0);
            float s0 = 1.0f/(1.0f + e0);
            float sc = low ? -2.0f : -1.0f;
            float e1 = __expf(sc*z1);
            float rr = 1.0f/(1.0f + e1);
            float act = low ? (1.0f - e1)*rr : rr;
            float pa = s0*act;
            float po = __shfl_xor(pa, 32);
            c = s0*c + po;
            float e2 = __expf(-2.0f*c);
            float th = (1.0f - e2)/(1.0f + e2);
            hreg = act*th;
        }
        if (!low){
            hrow[b][lane - 32] = hreg;
            seq[((size_t)b*N_STK + j)*UNITS + (lane - 32)] = hreg;
        }
    } else if (wv == 2){
        int local = 0;
        for (int jj = lane; jj < N_STK; jj += 64){
            unsigned p = patof(rel + ((size_t)j*N_STK + jj)*8);
            local += p ? 1 : 0;
        }
        #pragma unroll
        for (int d = 32; d; d >>= 1) local += __shfl_xor(local, d);
        if (lane == 0) invD[j] = 1.0f/(float)local;
        if (j < 64){
            int m = j & 15, half = (j >> 4) & 1, k = j >> 5;
            const float* W = hop_w1 + (size_t)k*INP*INP;
            int base = 2*UNITS + (half ? 4 : 0);
            for (int p = lane; p < INP; p += 64){
                float acc = half ? 0.0f : hop_b1[k*INP + p];
                #pragma unroll
                for (int q = 0; q < 4; q++)
                    if ((m >> q) & 1) acc += W[(base + q)*INP + p];
                (half ? luthi : lutlo)[(k*16 + m)*INP + p] = acc;
            }
        }
    } else {
        unsigned char pv[12];
        int c = 0;
        #pragma unroll
        for (int r = 0; r < 12; r++){
            int i = lane*12 + r;
            unsigned p = patof(rel + ((size_t)i*N_STK + j)*8);
            pv[r] = (unsigned char)p;
            c += p ? 1 : 0;
        }
        int sc = c;
        #pragma unroll
        for (int off = 1; off < 64; off <<= 1){
            int v = __shfl_up(sc, off);
            if (lane >= off) sc += v;
        }
        int slot = sc - c;
        #pragma unroll
        for (int r = 0; r < 12; r++)
            if (pv[r]) list[(size_t)j*N_STK + (slot++)] = (unsigned)(((lane*12 + r) << 8) | pv[r]);
        int total = __shfl(sc, 63);
        if (lane == 0) cnt[j] = total;
    }
    __syncthreads();
    if (tid < 2*INP){
        int b = tid/INP, p = tid%INP;
        float si = 0.0f, sj = 0.0f;
        #pragma unroll
        for (int u = 0; u < UNITS; u++){
            float ev = hrow[b][u];
            si += ev * hop_w1[u*INP + p];
            sj += ev * hop_w1[(UNITS + u)*INP + p];
        }
        size_t o = ((size_t)b*N_STK + j)*INP + p;
        xi0[o] = si; xj0[o] = sj;
    }
}

// ---------------------------------------------------------------------------
// col kernel v3: block = (column j, batch b). Async double-buffered pipeline:
// stage chunk c+1 via global_load_lds WHILE computing chunk c from LDS.
// 4 threads per entry (18 elements each, interleaved aligned float4 slices).
// One barrier per chunk. MODE 0: eout=ein*s + xi/xj_next.  MODE 1: FC head.
template<int MODE>
__global__ __launch_bounds__(256) void col_kernel(const float* __restrict__ xi,
        const float* __restrict__ xj,
        const float* __restrict__ lutlo_k, const float* __restrict__ luthi_k,
        const float* __restrict__ w2, const float* __restrict__ b2,
        const unsigned* __restrict__ list, const int* __restrict__ cnt,
        const float* __restrict__ invD,
        const float* __restrict__ ein, float* __restrict__ eout,
        const float* __restrict__ W1next, float* __restrict__ xi_next, float* __restrict__ xj_next,
        const float* __restrict__ seqg, const float* __restrict__ fw1,
        const float* __restrict__ fb1, const float* __restrict__ fw2,
        const float* __restrict__ fb2, float* __restrict__ outp){
    int j = blockIdx.x, b = blockIdx.y, tid = threadIdx.x;
    int cn = cnt[j];
    __shared__ float xi_buf[2][CHUNK*LROW];  // 2*64*76*4 = 38912 B, padded rows
    __shared__ float xjlo_sh[16*INP];        // xj[b,j,:] + lutlo[m,:]
    __shared__ float hi_sh[16*INP];
    __shared__ float red[4];
    __shared__ float sval;
    __shared__ float ep_sh[64];

    const float* xib = xi + (size_t)b*N_STK*INP;
    const unsigned* ljp = list + (size_t)j*N_STK;

    for (int idx = tid; idx < 16*INP; idx += 256){
        xjlo_sh[idx] = lutlo_k[idx] + xj[((size_t)b*N_STK + j)*INP + (idx % INP)];
        hi_sh[idx]   = luthi_k[idx];
    }
    int e4 = tid >> 2, qt = tid & 3;
    // w2 slices this thread needs: dw {qt*4+16k, k<4} (+ {64+qt*4} for qt<2)
    float4 w2r[5];
    #pragma unroll
    for (int k = 0; k < 4; k++) w2r[k] = *reinterpret_cast<const float4*>(w2 + qt*4 + 16*k);
    w2r[4] = (qt < 2) ? *reinterpret_cast<const float4*>(w2 + 64 + qt*4)
                      : make_float4(0.f,0.f,0.f,0.f);
    float b2v = b2[0];

    int nch = (cn + CHUNK - 1)/CHUNK;

    // async stage of chunk c into buffer sb: slots u = e*NSLC + sl, dest = u*16B
    auto stage = [&](int c, int sb){
        int base = c*CHUNK;
        float* dst = &xi_buf[sb][0];
        #pragma unroll
        for (int r = 0; r < 4; r++){
            int u = r*256 + tid;
            int eu = u/NSLC, sl = u - eu*NSLC;
            int idx = base + eu; if (idx > cn - 1) idx = cn - 1;
            int i = (int)(ljp[idx] >> 8);
            int off = (sl < 18) ? sl*4 : 0;     // pad slice: dummy load
            async_cp16(xib + (size_t)i*INP + off, dst + u*4);
        }
        {   // tail: slots 1024..1215 (waves 0-2 partially; branch wave-clean)
            int u = 1024 + tid;
            if (u < CHUNK*NSLC){
                int eu = u/NSLC, sl = u - eu*NSLC;
                int idx = base + eu; if (idx > cn - 1) idx = cn - 1;
                int i = (int)(ljp[idx] >> 8);
                int off = (sl < 18) ? sl*4 : 0;
                async_cp16(xib + (size_t)i*INP + off, dst + u*4);
            }
        }
    };

    stage(0, 0);
    __syncthreads();   // covers xjlo/hi stores + async chunk-0 (vmcnt drain)

    float accb = 0.0f;
    for (int c = 0; c < nch; c++){
        if (c + 1 < nch) stage(c + 1, (c + 1) & 1);
        int idx = c*CHUNK + e4;
        bool alive = idx < cn;
        unsigned ent = ljp[alive ? idx : cn - 1];
        int i = (int)(ent >> 8);
        int mlo = (int)(ent & 15u), mhi = (int)((ent >> 4) & 15u);
        const float* xr = &xi_buf[c & 1][e4*LROW];
        const float* jr = &xjlo_sh[mlo*INP];
        const float* hr = &hi_sh[mhi*INP];
        float acc = 0.0f;
        #pragma unroll
        for (int k = 0; k < 4; k++){
            int o = qt*4 + 16*k;
            float4 xv = *reinterpret_cast<const float4*>(xr + o);
            float4 jv = *reinterpret_cast<const float4*>(jr + o);
            float4 hv = *reinterpret_cast<const float4*>(hr + o);
            float4 w  = w2r[k];
            acc += lrelu(xv.x + jv.x + hv.x)*w.x;
            acc += lrelu(xv.y + jv.y + hv.y)*w.y;
            acc += lrelu(xv.z + jv.z + hv.z)*w.z;
            acc += lrelu(xv.w + jv.w + hv.w)*w.w;
        }
        if (qt < 2){
            int o = 64 + qt*4;
            float4 xv = *reinterpret_cast<const float4*>(xr + o);
            float4 jv = *reinterpret_cast<const float4*>(jr + o);
            float4 hv = *reinterpret_cast<const float4*>(hr + o);
            float4 w  = w2r[4];
            acc += lrelu(xv.x + jv.x + hv.x)*w.x;
            acc += lrelu(xv.y + jv.y + hv.y)*w.y;
            acc += lrelu(xv.z + jv.z + hv.z)*w.z;
            acc += lrelu(xv.w + jv.w + hv.w)*w.w;
        }
        acc += __shfl_xor(acc, 1);
        acc += __shfl_xor(acc, 2);
        if (alive && qt == 0) accb += lrelu(acc + b2v)*invD[i];
        __syncthreads();   // chunk c readers done; chunk c+1 staged (vmcnt)
    }
    // accb nonzero only on qt==0 lanes; full-wave xor reduce then cross-wave
    #pragma unroll
    for (int d = 1; d < 64; d <<= 1) accb += __shfl_xor(accb, d);
    if ((tid & 63) == 0) red[tid >> 6] = accb;
    __syncthreads();
    if (tid == 0) sval = red[0] + red[1] + red[2] + red[3];
    __syncthreads();

    if (MODE == 0){
        if (tid < 32){
            size_t o = ((size_t)b*N_STK + j)*UNITS + tid;
            float ev = ein[o]*sval;
            ep_sh[tid] = ev;
            eout[o] = ev;
        }
        __syncthreads();
        if (tid < INP){
            float si = 0.0f, sj = 0.0f;
            #pragma unroll
            for (int u = 0; u < UNITS; u++){
                float ev = ep_sh[u];
                si += ev * W1next[u*INP + tid];
                sj += ev * W1next[(UNITS + u)*INP + tid];
            }
            size_t o = ((size_t)b*N_STK + j)*INP + tid;
            xi_next[o] = si; xj_next[o] = sj;
        }
    } else {
        if (tid < 32){
            size_t o = ((size_t)b*N_STK + j)*UNITS + tid;
            ep_sh[32 + tid] = ein[o]*sval;
            ep_sh[tid] = seqg[o];
        }
        __syncthreads();
        if (tid < 64){
            float acc = fb1[tid];
            #pragma unroll 8
            for (int d = 0; d < 64; d++) acc += ep_sh[d]*fw1[d*64 + tid];
            float prod = lrelu(acc)*fw2[tid];
            prod += __shfl_xor(prod, 32);
            prod += __shfl_xor(prod, 16);
            prod += __shfl_xor(prod, 8);
            prod += __shfl_xor(prod, 4);
            prod += __shfl_xor(prod, 2);
            prod += __shfl_xor(prod, 1);
            if (tid == 0) outp[b*N_STK + j] = lrelu(prod + fb2[0]);
        }
    }
}

// ---------------------------------------------------------------------------
extern "C" void kernel_launch(void* const* d_in, const int* in_sizes, int n_in,
                              void* d_out, int out_size, void* d_ws, size_t ws_size,
                              hipStream_t stream){
    const float* input_data = (const float*)d_in[0];
    const float* rel        = (const float*)d_in[1];
    const float* lstm_Wih   = (const float*)d_in[2];
    const float* lstm_Whh   = (const float*)d_in[3];
    const float* lstm_bih   = (const float*)d_in[4];
    const float* lstm_bhh   = (const float*)d_in[5];
    const float* hop_w1     = (const float*)d_in[6];
    const float* hop_b1     = (const float*)d_in[7];
    const float* hop_w2     = (const float*)d_in[8];
    const float* hop_b2     = (const float*)d_in[9];
    const float* fn_w1      = (const float*)d_in[10];
    const float* fn_b1      = (const float*)d_in[11];
    const float* fn_w2      = (const float*)d_in[12];
    const float* fn_b2      = (const float*)d_in[13];
    float* out = (float*)d_out;

    float* ws    = (float*)d_ws;
    float* seq   = ws;                    // 49152
    float* eA    = seq   + 49152;         // 49152
    float* xi0   = eA    + 49152;         // 110592
    float* xj0   = xi0   + 110592;
    float* xi1   = xj0   + 110592;
    float* xj1   = xi1   + 110592;
    float* lutlo = xj1   + 110592;        // 2304
    float* luthi = lutlo + 2304;
    float* invD  = luthi + 2304;          // 768
    int*   cnt   = (int*)(invD + 768);    // 768
    unsigned* list = (unsigned*)(cnt + 768);  // 768*768 u32

    k1_kernel<<<N_STK, 256, 0, stream>>>(rel, input_data, lstm_Wih, lstm_Whh,
            lstm_bih, lstm_bhh, hop_w1, hop_b1,
            seq, invD, cnt, list, lutlo, luthi, xi0, xj0);

    dim3 cgrid(N_STK, BATCH);
    col_kernel<0><<<cgrid, 256, 0, stream>>>(xi0, xj0, lutlo, luthi,
            hop_w2, hop_b2, list, cnt, invD,
            seq, eA, hop_w1 + INP*INP, xi1, xj1,
            nullptr, nullptr, nullptr, nullptr, nullptr, nullptr);

    col_kernel<1><<<cgrid, 256, 0, stream>>>(xi1, xj1, lutlo + 16*INP, luthi + 16*INP,
            hop_w2 + INP, hop_b2 + 1, list, cnt, invD,
            eA, nullptr, nullptr, nullptr, nullptr,
            seq, fn_w1, fn_b1, fn_w2, fn_b2, out);
}

// Round 6
// 166.864 us; speedup vs baseline: 1.2361x; 1.0080x over previous
//
#include <hip/hip_runtime.h>

#define N_STK 768
#define BATCH 2
#define WIN   32
#define FEAT  4
#define UNITS 32
#define INP   72      // 2U + K
#define GCOL  3       // columns per col_kernel block
#define NPH   6       // row phases
#define PROWS 128     // rows per phase (NPH*PROWS = N_STK)
#define LROW  76      // padded LDS row stride (dwords)
#define NSLC  19      // 16B slices per padded row (slice 18 = pad)

__device__ __forceinline__ float lrelu(float v){ return v > 0.0f ? v : 0.01f*v; }
__device__ __forceinline__ float lanebcast(float v, int l){
    return __int_as_float(__builtin_amdgcn_readlane(__float_as_int(v), l));
}
__device__ __forceinline__ unsigned patof(const float* __restrict__ p){
    float4 a = *reinterpret_cast<const float4*>(p);
    float4 b = *reinterpret_cast<const float4*>(p + 4);
    unsigned m = 0;
    m |= (a.x != 0.0f) ? 1u   : 0u;
    m |= (a.y != 0.0f) ? 2u   : 0u;
    m |= (a.z != 0.0f) ? 4u   : 0u;
    m |= (a.w != 0.0f) ? 8u   : 0u;
    m |= (b.x != 0.0f) ? 16u  : 0u;
    m |= (b.y != 0.0f) ? 32u  : 0u;
    m |= (b.z != 0.0f) ? 64u  : 0u;
    m |= (b.w != 0.0f) ? 128u : 0u;
    return m;
}
// async 16B global->LDS; LDS dest = wave-uniform base + lane*16 (our slot map).
__device__ __forceinline__ void async_cp16(const float* g, float* l){
    __builtin_amdgcn_global_load_lds(
        (const __attribute__((address_space(1))) unsigned int*)g,
        (__attribute__((address_space(3))) unsigned int*)l,
        16, 0, 0);
}

// ---------------------------------------------------------------------------
// K1 (unchanged): block j computes LSTM (waves 0,1), invD + LUT (wave 2),
// CSC column (wave 3), then xi0/xj0 rows for (0,j),(1,j).
__global__ __launch_bounds__(256) void k1_kernel(const float* __restrict__ rel,
        const float* __restrict__ x, const float* __restrict__ Wih,
        const float* __restrict__ Whh, const float* __restrict__ bih,
        const float* __restrict__ bhh, const float* __restrict__ hop_w1,
        const float* __restrict__ hop_b1,
        float* __restrict__ seq, float* __restrict__ invD, int* __restrict__ cnt,
        unsigned* __restrict__ list, float* __restrict__ lutlo, float* __restrict__ luthi,
        float* __restrict__ xi0, float* __restrict__ xj0){
    int j = blockIdx.x, tid = threadIdx.x;
    int wv = tid >> 6, lane = tid & 63;
    __shared__ float hrow[2][UNITS];

    if (wv < 2){
        int b = wv;
        int r0 = lane, r1 = 64 + lane;
        bool low = (lane < 32);
        float4 wi0 = *reinterpret_cast<const float4*>(Wih + r0*FEAT);
        float4 wi1 = *reinterpret_cast<const float4*>(Wih + r1*FEAT);
        float bb0 = bih[r0] + bhh[r0];
        float bb1 = bih[r1] + bhh[r1];
        float4 W0[8], W1[8];
        #pragma unroll
        for (int q = 0; q < 8; q++){
            W0[q] = *reinterpret_cast<const float4*>(Whh + r0*UNITS + q*4);
            W1[q] = *reinterpret_cast<const float4*>(Whh + r1*UNITS + q*4);
        }
        float4 xv = make_float4(0.f, 0.f, 0.f, 0.f);
        if (low) xv = *reinterpret_cast<const float4*>(x + ((size_t)(b*WIN + lane)*N_STK + j)*FEAT);
        float hreg = 0.0f, c = 0.0f;
        #pragma unroll 1
        for (int t = 0; t < WIN; t++){
            float xb0 = lanebcast(xv.x, t), xb1 = lanebcast(xv.y, t);
            float xb2 = lanebcast(xv.z, t), xb3 = lanebcast(xv.w, t);
            float z0a = bb0 + wi0.x*xb0 + wi0.z*xb2;
            float z0b =       wi0.y*xb1 + wi0.w*xb3;
            float z1a = bb1 + wi1.x*xb0 + wi1.z*xb2;
            float z1b =       wi1.y*xb1 + wi1.w*xb3;
            #pragma unroll
            for (int q = 0; q < 8; q++){
                float h0 = lanebcast(hreg, 32 + q*4 + 0);
                float h1 = lanebcast(hreg, 32 + q*4 + 1);
                float h2 = lanebcast(hreg, 32 + q*4 + 2);
                float h3 = lanebcast(hreg, 32 + q*4 + 3);
                z0a += W0[q].x*h0; z0b += W0[q].y*h1;
                z0a += W0[q].z*h2; z0b += W0[q].w*h3;
                z1a += W1[q].x*h0; z1b += W1[q].y*h1;
                z1a += W1[q].z*h2; z1b += W1[q].w*h3;
            }
            float z0 = z0a + z0b, z1 = z1a + z1b;
            float e0 = __expf(-z0);
            float s0 = 1.0f/(1.0f + e0);
            float sc = low ? -2.0f : -1.0f;
            float e1 = __expf(sc*z1);
            float rr = 1.0f/(1.0f + e1);
            float act = low ? (1.0f - e1)*rr : rr;
            float pa = s0*act;
            float po = __shfl_xor(pa, 32);
            c = s0*c + po;
            float e2 = __expf(-2.0f*c);
            float th = (1.0f - e2)/(1.0f + e2);
            hreg = act*th;
        }
        if (!low){
            hrow[b][lane - 32] = hreg;
            seq[((size_t)b*N_STK + j)*UNITS + (lane - 32)] = hreg;
        }
    } else if (wv == 2){
        int local = 0;
        for (int jj = lane; jj < N_STK; jj += 64){
            unsigned p = patof(rel + ((size_t)j*N_STK + jj)*8);
            local += p ? 1 : 0;
        }
        #pragma unroll
        for (int d = 32; d; d >>= 1) local += __shfl_xor(local, d);
        if (lane == 0) invD[j] = 1.0f/(float)local;
        if (j < 64){
            int m = j & 15, half = (j >> 4) & 1, k = j >> 5;
            const float* W = hop_w1 + (size_t)k*INP*INP;
            int base = 2*UNITS + (half ? 4 : 0);
            for (int p = lane; p < INP; p += 64){
                float acc = half ? 0.0f : hop_b1[k*INP + p];
                #pragma unroll
                for (int q = 0; q < 4; q++)
                    if ((m >> q) & 1) acc += W[(base + q)*INP + p];
                (half ? luthi : lutlo)[(k*16 + m)*INP + p] = acc;
            }
        }
    } else {
        unsigned char pv[12];
        int c = 0;
        #pragma unroll
        for (int r = 0; r < 12; r++){
            int i = lane*12 + r;
            unsigned p = patof(rel + ((size_t)i*N_STK + j)*8);
            pv[r] = (unsigned char)p;
            c += p ? 1 : 0;
        }
        int sc = c;
        #pragma unroll
        for (int off = 1; off < 64; off <<= 1){
            int v = __shfl_up(sc, off);
            if (lane >= off) sc += v;
        }
        int slot = sc - c;
        #pragma unroll
        for (int r = 0; r < 12; r++)
            if (pv[r]) list[(size_t)j*N_STK + (slot++)] = (unsigned)(((lane*12 + r) << 8) | pv[r]);
        int total = __shfl(sc, 63);
        if (lane == 0) cnt[j] = total;
    }
    __syncthreads();
    if (tid < 2*INP){
        int b = tid/INP, p = tid%INP;
        float si = 0.0f, sj = 0.0f;
        #pragma unroll
        for (int u = 0; u < UNITS; u++){
            float ev = hrow[b][u];
            si += ev * hop_w1[u*INP + p];
            sj += ev * hop_w1[(UNITS + u)*INP + p];
        }
        size_t o = ((size_t)b*N_STK + j)*INP + p;
        xi0[o] = si; xj0[o] = sj;
    }
}

// ---------------------------------------------------------------------------
// col kernel v4: block = (batch b, 3 columns). DENSE row-phase streaming:
// 6 phases of 128 xi rows staged densely into LDS via async copies (zero
// scattered VMEM); per phase, process exactly the CSC entries with i in the
// phase (i-sorted list, binary-searched boundaries), flattened across the 3
// columns for balance. 2 threads/entry (36-dw halves), shfl-combined.
// MODE 0: eout=ein*s + xi/xj_next rows.  MODE 1: FC head -> out.
template<int MODE>
__global__ __launch_bounds__(256) void col_kernel(const float* __restrict__ xi,
        const float* __restrict__ xj,
        const float* __restrict__ lutlo_k, const float* __restrict__ luthi_k,
        const float* __restrict__ w2, const float* __restrict__ b2,
        const unsigned* __restrict__ list, const int* __restrict__ cnt,
        const float* __restrict__ invD,
        const float* __restrict__ ein, float* __restrict__ eout,
        const float* __restrict__ W1next, float* __restrict__ xi_next, float* __restrict__ xj_next,
        const float* __restrict__ seqg, const float* __restrict__ fw1,
        const float* __restrict__ fb1, const float* __restrict__ fw2,
        const float* __restrict__ fb2, float* __restrict__ outp){
    int g = blockIdx.x, b = blockIdx.y, tid = threadIdx.x;
    int j0 = g*GCOL;
    __shared__ float xi_sh[PROWS*LROW];      // 38912 B, dense phase of xi rows
    __shared__ float lo_sh[16*LROW];         // 4864 B
    __shared__ float hi_sh[16*LROW];         // 4864 B
    __shared__ float xj_sh[GCOL*LROW];       //  912 B
    __shared__ int   bnd_sh[GCOL][NPH+1];
    __shared__ float red_sh[GCOL][4];
    __shared__ float sval[GCOL];
    __shared__ float ep_sh[GCOL][64];

    const float* xib = xi + (size_t)b*N_STK*INP;

    // small sync staging: luts (padded rows) + xj rows
    for (int idx = tid; idx < 16*18; idx += 256){
        int m = idx/18, q = (idx - m*18)*4;
        *reinterpret_cast<float4*>(&lo_sh[m*LROW + q]) = *reinterpret_cast<const float4*>(lutlo_k + m*INP + q);
        *reinterpret_cast<float4*>(&hi_sh[m*LROW + q]) = *reinterpret_cast<const float4*>(luthi_k + m*INP + q);
    }
    if (tid < GCOL*18){
        int c = tid/18, q = (tid - c*18)*4;
        *reinterpret_cast<float4*>(&xj_sh[c*LROW + q]) =
            *reinterpret_cast<const float4*>(xj + ((size_t)b*N_STK + j0 + c)*INP + q);
    }
    // phase boundaries: first list index with i >= ph*PROWS
    if (tid < GCOL*(NPH+1)){
        int c = tid/(NPH+1), ph = tid - c*(NPH+1);
        const unsigned* lj = list + (size_t)(j0+c)*N_STK;
        int lo = 0, hi = cnt[j0+c];
        int thr = ph*PROWS;
        while (lo < hi){ int md = (lo+hi)>>1; if ((int)(lj[md]>>8) < thr) lo = md+1; else hi = md; }
        bnd_sh[c][ph] = lo;
    }

    int e2 = tid >> 1, hf = tid & 1;
    float4 w2r[9];
    #pragma unroll
    for (int q = 0; q < 9; q++) w2r[q] = *reinterpret_cast<const float4*>(w2 + hf*36 + q*4);
    float b2v = b2[0];
    float acc0 = 0.0f, acc1 = 0.0f, acc2 = 0.0f;

    for (int ph = 0; ph < NPH; ph++){
        // dense async stage of xi rows [ph*PROWS, ph*PROWS+PROWS)
        #pragma unroll
        for (int it = 0; it < 10; it++){
            int u = it*256 + tid;
            if (u < PROWS*NSLC){
                int row = u/NSLC, sl = u - row*NSLC;
                int off = (sl < 18) ? sl*4 : 0;
                async_cp16(xib + (size_t)(ph*PROWS + row)*INP + off, &xi_sh[0] + (size_t)u*4);
            }
        }
        __syncthreads();   // drains async stage (+ first pass: luts/xj/bnd)

        int c0b = bnd_sh[0][ph], c0n = bnd_sh[0][ph+1] - c0b;
        int c1b = bnd_sh[1][ph], c1n = bnd_sh[1][ph+1] - c1b;
        int c2b = bnd_sh[2][ph], c2n = bnd_sh[2][ph+1] - c2b;
        int off1 = c0n, off2 = c0n + c1n, tot = off2 + c2n;
        for (int gsl = e2; gsl < tot; gsl += 128){
            int c, e;
            if (gsl < off1){ c = 0; e = c0b + gsl; }
            else if (gsl < off2){ c = 1; e = c1b + (gsl - off1); }
            else { c = 2; e = c2b + (gsl - off2); }
            unsigned ent = list[(size_t)(j0+c)*N_STK + e];
            int ig = (int)(ent >> 8);
            int mlo = (int)(ent & 15u), mhi = (int)((ent >> 4) & 15u);
            const float* xr = &xi_sh[(ig - ph*PROWS)*LROW + hf*36];
            const float* jr = &xj_sh[c*LROW + hf*36];
            const float* lr = &lo_sh[mlo*LROW + hf*36];
            const float* hr = &hi_sh[mhi*LROW + hf*36];
            float dot = 0.0f;
            #pragma unroll
            for (int q = 0; q < 9; q++){
                float4 xv = *reinterpret_cast<const float4*>(xr + q*4);
                float4 jv = *reinterpret_cast<const float4*>(jr + q*4);
                float4 lv = *reinterpret_cast<const float4*>(lr + q*4);
                float4 hv = *reinterpret_cast<const float4*>(hr + q*4);
                float4 w  = w2r[q];
                dot += lrelu(xv.x + jv.x + lv.x + hv.x)*w.x;
                dot += lrelu(xv.y + jv.y + lv.y + hv.y)*w.y;
                dot += lrelu(xv.z + jv.z + lv.z + hv.z)*w.z;
                dot += lrelu(xv.w + jv.w + lv.w + hv.w)*w.w;
            }
            dot += __shfl_xor(dot, 1);
            if (hf == 0){
                float v = lrelu(dot + b2v)*invD[ig];
                acc0 += (c == 0) ? v : 0.0f;
                acc1 += (c == 1) ? v : 0.0f;
                acc2 += (c == 2) ? v : 0.0f;
            }
        }
        __syncthreads();   // phase readers done before restage
    }

    #pragma unroll
    for (int d = 1; d < 64; d <<= 1){
        acc0 += __shfl_xor(acc0, d);
        acc1 += __shfl_xor(acc1, d);
        acc2 += __shfl_xor(acc2, d);
    }
    int w = tid >> 6;
    if ((tid & 63) == 0){ red_sh[0][w] = acc0; red_sh[1][w] = acc1; red_sh[2][w] = acc2; }
    __syncthreads();
    if (tid < GCOL) sval[tid] = red_sh[tid][0] + red_sh[tid][1] + red_sh[tid][2] + red_sh[tid][3];
    __syncthreads();

    if (MODE == 0){
        if (tid < GCOL*32){
            int c = tid >> 5, u = tid & 31;
            size_t o = ((size_t)b*N_STK + j0 + c)*UNITS + u;
            float ev = ein[o]*sval[c];
            ep_sh[c][u] = ev;
            eout[o] = ev;
        }
        __syncthreads();
        if (tid < GCOL*INP){
            int c = tid/INP, p = tid - c*INP;
            float si = 0.0f, sj = 0.0f;
            #pragma unroll
            for (int u = 0; u < UNITS; u++){
                float ev = ep_sh[c][u];
                si += ev * W1next[u*INP + p];
                sj += ev * W1next[(UNITS + u)*INP + p];
            }
            size_t o = ((size_t)b*N_STK + j0 + c)*INP + p;
            xi_next[o] = si; xj_next[o] = sj;
        }
    } else {
        if (tid < GCOL*32){
            int c = tid >> 5, u = tid & 31;
            size_t o = ((size_t)b*N_STK + j0 + c)*UNITS + u;
            ep_sh[c][32 + u] = ein[o]*sval[c];
            ep_sh[c][u] = seqg[o];
        }
        __syncthreads();
        if (tid < GCOL*64){
            int c = tid >> 6, u = tid & 63;   // wave-aligned per column
            float acc = fb1[u];
            #pragma unroll 8
            for (int d = 0; d < 64; d++) acc += ep_sh[c][d]*fw1[d*64 + u];
            float prod = lrelu(acc)*fw2[u];
            prod += __shfl_xor(prod, 32);
            prod += __shfl_xor(prod, 16);
            prod += __shfl_xor(prod, 8);
            prod += __shfl_xor(prod, 4);
            prod += __shfl_xor(prod, 2);
            prod += __shfl_xor(prod, 1);
            if (u == 0) outp[b*N_STK + j0 + c] = lrelu(prod + fb2[0]);
        }
    }
}

// ---------------------------------------------------------------------------
extern "C" void kernel_launch(void* const* d_in, const int* in_sizes, int n_in,
                              void* d_out, int out_size, void* d_ws, size_t ws_size,
                              hipStream_t stream){
    const float* input_data = (const float*)d_in[0];
    const float* rel        = (const float*)d_in[1];
    const float* lstm_Wih   = (const float*)d_in[2];
    const float* lstm_Whh   = (const float*)d_in[3];
    const float* lstm_bih   = (const float*)d_in[4];
    const float* lstm_bhh   = (const float*)d_in[5];
    const float* hop_w1     = (const float*)d_in[6];
    const float* hop_b1     = (const float*)d_in[7];
    const float* hop_w2     = (const float*)d_in[8];
    const float* hop_b2     = (const float*)d_in[9];
    const float* fn_w1      = (const float*)d_in[10];
    const float* fn_b1      = (const float*)d_in[11];
    const float* fn_w2      = (const float*)d_in[12];
    const float* fn_b2      = (const float*)d_in[13];
    float* out = (float*)d_out;

    float* ws    = (float*)d_ws;
    float* seq   = ws;                    // 49152
    float* eA    = seq   + 49152;         // 49152
    float* xi0   = eA    + 49152;         // 110592
    float* xj0   = xi0   + 110592;
    float* xi1   = xj0   + 110592;
    float* xj1   = xi1   + 110592;
    float* lutlo = xj1   + 110592;        // 2304
    float* luthi = lutlo + 2304;
    float* invD  = luthi + 2304;          // 768
    int*   cnt   = (int*)(invD + 768);    // 768
    unsigned* list = (unsigned*)(cnt + 768);  // 768*768 u32

    k1_kernel<<<N_STK, 256, 0, stream>>>(rel, input_data, lstm_Wih, lstm_Whh,
            lstm_bih, lstm_bhh, hop_w1, hop_b1,
            seq, invD, cnt, list, lutlo, luthi, xi0, xj0);

    dim3 cgrid(N_STK/GCOL, BATCH);
    col_kernel<0><<<cgrid, 256, 0, stream>>>(xi0, xj0, lutlo, luthi,
            hop_w2, hop_b2, list, cnt, invD,
            seq, eA, hop_w1 + INP*INP, xi1, xj1,
            nullptr, nullptr, nullptr, nullptr, nullptr, nullptr);

    col_kernel<1><<<cgrid, 256, 0, stream>>>(xi1, xj1, lutlo + 16*INP, luthi + 16*INP,
            hop_w2 + INP, hop_b2 + 1, list, cnt, invD,
            eA, nullptr, nullptr, nullptr, nullptr,
            seq, fn_w1, fn_b1, fn_w2, fn_b2, out);
}

// Round 7
// 148.587 us; speedup vs baseline: 1.3881x; 1.1230x over previous
//
#include <hip/hip_runtime.h>

#define N_STK 768
#define BATCH 2
#define WIN   32
#define FEAT  4
#define UNITS 32
#define INP   72      // 2U + K
#define LROW  76      // padded LDS row stride (dwords), 16B-aligned
#define NSLC  19      // 16B slices per padded row (slice 18 = pad, dummy load)
#define IPH   64      // xi rows per i-phase block
#define JCR   24      // columns per block
#define NPHI  12      // 768/64
#define NCR   32      // 768/24

__device__ __forceinline__ float lrelu(float v){ return v > 0.0f ? v : 0.01f*v; }
__device__ __forceinline__ float lanebcast(float v, int l){
    return __int_as_float(__builtin_amdgcn_readlane(__float_as_int(v), l));
}
__device__ __forceinline__ unsigned patof(const float* __restrict__ p){
    float4 a = *reinterpret_cast<const float4*>(p);
    float4 b = *reinterpret_cast<const float4*>(p + 4);
    unsigned m = 0;
    m |= (a.x != 0.0f) ? 1u   : 0u;
    m |= (a.y != 0.0f) ? 2u   : 0u;
    m |= (a.z != 0.0f) ? 4u   : 0u;
    m |= (a.w != 0.0f) ? 8u   : 0u;
    m |= (b.x != 0.0f) ? 16u  : 0u;
    m |= (b.y != 0.0f) ? 32u  : 0u;
    m |= (b.z != 0.0f) ? 64u  : 0u;
    m |= (b.w != 0.0f) ? 128u : 0u;
    return m;
}
// async 16B global->LDS; LDS dest = wave-uniform base + lane*16 (slot maps keep this).
__device__ __forceinline__ void async_cp16(const float* g, float* l){
    __builtin_amdgcn_global_load_lds(
        (const __attribute__((address_space(1))) unsigned int*)g,
        (__attribute__((address_space(3))) unsigned int*)l,
        16, 0, 0);
}

// ---------------------------------------------------------------------------
// K1: block j:
//   waves 0,1 : LSTM for (b=0,j),(b=1,j)  [registers + readlane, no barriers]
//   waves 2,3 : pattern row j of rel (coalesced, read ONCE) -> P bytes + count
//   epilogue  : invD[j], zero s0, LUT slices (j<64), xi0/xj0 rows
__global__ __launch_bounds__(256) void k1_kernel(const float* __restrict__ rel,
        const float* __restrict__ x, const float* __restrict__ Wih,
        const float* __restrict__ Whh, const float* __restrict__ bih,
        const float* __restrict__ bhh, const float* __restrict__ hop_w1,
        const float* __restrict__ hop_b1,
        float* __restrict__ seq, float* __restrict__ invD,
        unsigned char* __restrict__ Pout,
        float* __restrict__ lutlo, float* __restrict__ luthi,
        float* __restrict__ xi0, float* __restrict__ xj0,
        float* __restrict__ s0){
    int j = blockIdx.x, tid = threadIdx.x;
    int wv = tid >> 6, lane = tid & 63;
    __shared__ float hrow[2][UNITS];
    __shared__ int cw_sh[2];

    if (wv < 2){
        int b = wv;
        int r0 = lane, r1 = 64 + lane;
        bool low = (lane < 32);
        float4 wi0 = *reinterpret_cast<const float4*>(Wih + r0*FEAT);
        float4 wi1 = *reinterpret_cast<const float4*>(Wih + r1*FEAT);
        float bb0 = bih[r0] + bhh[r0];
        float bb1 = bih[r1] + bhh[r1];
        float4 W0[8], W1[8];
        #pragma unroll
        for (int q = 0; q < 8; q++){
            W0[q] = *reinterpret_cast<const float4*>(Whh + r0*UNITS + q*4);
            W1[q] = *reinterpret_cast<const float4*>(Whh + r1*UNITS + q*4);
        }
        float4 xv = make_float4(0.f, 0.f, 0.f, 0.f);
        if (low) xv = *reinterpret_cast<const float4*>(x + ((size_t)(b*WIN + lane)*N_STK + j)*FEAT);
        float hreg = 0.0f, c = 0.0f;
        #pragma unroll 1
        for (int t = 0; t < WIN; t++){
            float xb0 = lanebcast(xv.x, t), xb1 = lanebcast(xv.y, t);
            float xb2 = lanebcast(xv.z, t), xb3 = lanebcast(xv.w, t);
            float z0a = bb0 + wi0.x*xb0 + wi0.z*xb2;
            float z0b =       wi0.y*xb1 + wi0.w*xb3;
            float z1a = bb1 + wi1.x*xb0 + wi1.z*xb2;
            float z1b =       wi1.y*xb1 + wi1.w*xb3;
            #pragma unroll
            for (int q = 0; q < 8; q++){
                float h0 = lanebcast(hreg, 32 + q*4 + 0);
                float h1 = lanebcast(hreg, 32 + q*4 + 1);
                float h2 = lanebcast(hreg, 32 + q*4 + 2);
                float h3 = lanebcast(hreg, 32 + q*4 + 3);
                z0a += W0[q].x*h0; z0b += W0[q].y*h1;
                z0a += W0[q].z*h2; z0b += W0[q].w*h3;
                z1a += W1[q].x*h0; z1b += W1[q].y*h1;
                z1a += W1[q].z*h2; z1b += W1[q].w*h3;
            }
            float z0 = z0a + z0b, z1 = z1a + z1b;
            float e0 = __expf(-z0);
            float s0g = 1.0f/(1.0f + e0);                // sig(i) / sig(f)
            float sc = low ? -2.0f : -1.0f;
            float e1 = __expf(sc*z1);
            float rr = 1.0f/(1.0f + e1);
            float act = low ? (1.0f - e1)*rr : rr;       // tanh(g) / sig(o)
            float pa = s0g*act;
            float po = __shfl_xor(pa, 32);
            c = s0g*c + po;
            float e2 = __expf(-2.0f*c);
            float th = (1.0f - e2)/(1.0f + e2);
            hreg = act*th;
        }
        if (!low){
            hrow[b][lane - 32] = hreg;
            seq[((size_t)b*N_STK + j)*UNITS + (lane - 32)] = hreg;
        }
    } else {
        // pattern row j, half the columns per wave, fully coalesced
        int half = wv - 2;
        int local = 0;
        #pragma unroll
        for (int k = 0; k < 6; k++){
            int col = half*384 + k*64 + lane;
            unsigned p = patof(rel + ((size_t)j*N_STK + col)*8);
            Pout[(size_t)j*N_STK + col] = (unsigned char)p;
            local += p ? 1 : 0;
        }
        #pragma unroll
        for (int d = 32; d; d >>= 1) local += __shfl_xor(local, d);
        if (lane == 0) cw_sh[half] = local;
    }
    __syncthreads();
    if (tid == 0){
        invD[j] = 1.0f/(float)(cw_sh[0] + cw_sh[1]);
        s0[j] = 0.0f; s0[N_STK + j] = 0.0f;
    }
    // LUT slices: blocks j<64 cover (k=j>>5, half=(j>>4)&1, m=j&15); 72 threads
    if (j < 64 && tid >= 144 && tid < 216){
        int p = tid - 144;
        int m = j & 15, half = (j >> 4) & 1, k = j >> 5;
        const float* W = hop_w1 + (size_t)k*INP*INP;
        float acc = half ? 0.0f : hop_b1[k*INP + p];
        int base = 2*UNITS + (half ? 4 : 0);
        #pragma unroll
        for (int q = 0; q < 4; q++)
            if ((m >> q) & 1) acc += W[(base + q)*INP + p];
        (half ? luthi : lutlo)[(k*16 + m)*INP + p] = acc;
    }
    // xi0/xj0 rows for (0,j),(1,j), hop-0 weights
    if (tid < 2*INP){
        int b = tid/INP, p = tid - b*INP;
        float si = 0.0f, sj = 0.0f;
        #pragma unroll
        for (int u = 0; u < UNITS; u++){
            float ev = hrow[b][u];
            si += ev * hop_w1[u*INP + p];
            sj += ev * hop_w1[(UNITS + u)*INP + p];
        }
        size_t o = ((size_t)b*N_STK + j)*INP + p;
        xi0[o] = si; xj0[o] = sj;
    }
}

// ---------------------------------------------------------------------------
// HOP kernel: block = (col-range 24, i-phase 64, batch). Stage ONCE:
// 64 xi rows + 24 xj rows + LUTs + invD slice (all dense async), enumerate
// the 64x24 P sub-block into an LDS entry list, compute per-column partials
// (2 lanes/entry, 36-dw halves), merge with 24 global atomics. 3 barriers.
__global__ __launch_bounds__(256) void hop_kernel(const float* __restrict__ xi,
        const float* __restrict__ xj,
        const float* __restrict__ lutlo_k, const float* __restrict__ luthi_k,
        const float* __restrict__ w2, const float* __restrict__ b2,
        const unsigned char* __restrict__ P, const float* __restrict__ invD,
        float* __restrict__ s_out){
    int cr = blockIdx.x, ip = blockIdx.y, b = blockIdx.z;
    int j0 = cr*JCR, i0 = ip*IPH, tid = threadIdx.x;
    __shared__ float xi_sh[IPH*LROW];        // 19456 B
    __shared__ float xj_sh[JCR*LROW];        //  7296 B
    __shared__ float lo_sh[16*LROW];         //  4864 B
    __shared__ float hi_sh[16*LROW];         //  4864 B
    __shared__ float invD_sh[IPH];
    __shared__ float acc_sh[JCR];
    __shared__ unsigned elist[IPH*JCR];      //  6144 B (hard upper bound)
    __shared__ int lcnt;

    const float* xib = xi + ((size_t)b*N_STK + i0)*INP;
    const float* xjb = xj + ((size_t)b*N_STK + j0)*INP;

    if (tid == 0) lcnt = 0;
    if (tid < JCR) acc_sh[tid] = 0.0f;
    __syncthreads();

    // ---- dense async staging (one exposed latency for the whole block) ----
    for (int u = tid; u < IPH*NSLC; u += 256){
        int r = u/NSLC, sl = u - r*NSLC;
        int off = (sl < 18) ? sl*4 : 0;
        async_cp16(xib + (size_t)r*INP + off, &xi_sh[0] + (size_t)u*4);
    }
    for (int u = tid; u < JCR*NSLC; u += 256){
        int r = u/NSLC, sl = u - r*NSLC;
        int off = (sl < 18) ? sl*4 : 0;
        async_cp16(xjb + (size_t)r*INP + off, &xj_sh[0] + (size_t)u*4);
    }
    for (int u = tid; u < 16*NSLC; u += 256){
        int r = u/NSLC, sl = u - r*NSLC;
        int off = (sl < 18) ? sl*4 : 0;
        async_cp16(lutlo_k + r*INP + off, &lo_sh[0] + (size_t)u*4);
    }
    for (int u = tid; u < 16*NSLC; u += 256){
        int r = u/NSLC, sl = u - r*NSLC;
        int off = (sl < 18) ? sl*4 : 0;
        async_cp16(luthi_k + r*INP + off, &hi_sh[0] + (size_t)u*4);
    }
    if (tid < IPH/4) async_cp16(invD + i0 + tid*4, &invD_sh[0] + tid*4);

    // ---- enumerate P sub-block into LDS entry list (overlaps staging) ----
    if (tid < IPH){
        const unsigned* prow = reinterpret_cast<const unsigned*>(P + (size_t)(i0 + tid)*N_STK + j0);
        unsigned w[6];
        #pragma unroll
        for (int k = 0; k < 6; k++) w[k] = prow[k];
        #pragma unroll
        for (int k = 0; k < 24; k++){
            unsigned pat = (w[k >> 2] >> ((k & 3)*8)) & 255u;
            if (pat){
                int pos = atomicAdd(&lcnt, 1);
                elist[pos] = ((unsigned)tid << 13) | ((unsigned)k << 8) | pat;
            }
        }
    }

    int hf = tid & 1;
    float4 w2r[9];
    #pragma unroll
    for (int q = 0; q < 9; q++) w2r[q] = *reinterpret_cast<const float4*>(w2 + hf*36 + q*4);
    float b2v = b2[0];
    __syncthreads();   // drains async staging + entry list

    int m = lcnt;
    for (int sl = tid >> 1; sl < m; sl += 128){
        unsigned ent = elist[sl];
        int il = ent >> 13, jl = (ent >> 8) & 31;
        int mlo = (int)(ent & 15u), mhi = (int)((ent >> 4) & 15u);
        const float* xr = &xi_sh[il*LROW + hf*36];
        const float* jr = &xj_sh[jl*LROW + hf*36];
        const float* lr = &lo_sh[mlo*LROW + hf*36];
        const float* hr = &hi_sh[mhi*LROW + hf*36];
        float dot = 0.0f;
        #pragma unroll
        for (int q = 0; q < 9; q++){
            float4 xv = *reinterpret_cast<const float4*>(xr + q*4);
            float4 jv = *reinterpret_cast<const float4*>(jr + q*4);
            float4 lv = *reinterpret_cast<const float4*>(lr + q*4);
            float4 hv = *reinterpret_cast<const float4*>(hr + q*4);
            float4 w  = w2r[q];
            dot += lrelu(xv.x + jv.x + lv.x + hv.x)*w.x;
            dot += lrelu(xv.y + jv.y + lv.y + hv.y)*w.y;
            dot += lrelu(xv.z + jv.z + lv.z + hv.z)*w.z;
            dot += lrelu(xv.w + jv.w + lv.w + hv.w)*w.w;
        }
        dot += __shfl_xor(dot, 1);
        if (hf == 0) atomicAdd(&acc_sh[jl], lrelu(dot + b2v)*invD_sh[il]);
    }
    __syncthreads();
    if (tid < JCR) atomicAdd(&s_out[b*N_STK + j0 + tid], acc_sh[tid]);
}

// ---------------------------------------------------------------------------
// Epilogues. MODE 0 (after hop0): eA = seq*s0, xi1/xj1 rows, zero s1.
// MODE 1 (after hop1): FC head on [seq, eA*s1] -> out.
template<int MODE>
__global__ __launch_bounds__(192) void ep_kernel(const float* __restrict__ sview,
        const float* __restrict__ ein, const float* __restrict__ seqg,
        float* __restrict__ eout,
        const float* __restrict__ W1next, float* __restrict__ xi_next,
        float* __restrict__ xj_next, float* __restrict__ s_next,
        const float* __restrict__ fw1, const float* __restrict__ fb1,
        const float* __restrict__ fw2, const float* __restrict__ fb2,
        float* __restrict__ outp){
    int j = blockIdx.x, tid = threadIdx.x;
    __shared__ float e_sh[2][64];
    if (tid < 64){
        int b = tid >> 5, u = tid & 31;
        size_t o = ((size_t)b*N_STK + j)*UNITS + u;
        float ev = ein[o]*sview[b*N_STK + j];
        if (MODE == 0){ e_sh[b][u] = ev; eout[o] = ev; }
        else          { e_sh[b][32 + u] = ev; e_sh[b][u] = seqg[o]; }
    }
    if (MODE == 0 && tid >= 160 && tid < 162) s_next[(tid - 160)*N_STK + j] = 0.0f;
    __syncthreads();
    if (MODE == 0){
        if (tid < 2*INP){
            int b = tid/INP, p = tid - b*INP;
            float si = 0.0f, sj = 0.0f;
            #pragma unroll
            for (int u = 0; u < UNITS; u++){
                float ev = e_sh[b][u];
                si += ev * W1next[u*INP + p];
                sj += ev * W1next[(UNITS + u)*INP + p];
            }
            size_t o = ((size_t)b*N_STK + j)*INP + p;
            xi_next[o] = si; xj_next[o] = sj;
        }
    } else {
        if (tid < 128){
            int b = tid >> 6, u = tid & 63;
            float acc = fb1[u];
            #pragma unroll 8
            for (int d = 0; d < 64; d++) acc += e_sh[b][d]*fw1[d*64 + u];
            float prod = lrelu(acc)*fw2[u];
            prod += __shfl_xor(prod, 32);
            prod += __shfl_xor(prod, 16);
            prod += __shfl_xor(prod, 8);
            prod += __shfl_xor(prod, 4);
            prod += __shfl_xor(prod, 2);
            prod += __shfl_xor(prod, 1);
            if (u == 0) outp[b*N_STK + j] = lrelu(prod + fb2[0]);
        }
    }
}

// ---------------------------------------------------------------------------
extern "C" void kernel_launch(void* const* d_in, const int* in_sizes, int n_in,
                              void* d_out, int out_size, void* d_ws, size_t ws_size,
                              hipStream_t stream){
    const float* input_data = (const float*)d_in[0];
    const float* rel        = (const float*)d_in[1];
    const float* lstm_Wih   = (const float*)d_in[2];
    const float* lstm_Whh   = (const float*)d_in[3];
    const float* lstm_bih   = (const float*)d_in[4];
    const float* lstm_bhh   = (const float*)d_in[5];
    const float* hop_w1     = (const float*)d_in[6];
    const float* hop_b1     = (const float*)d_in[7];
    const float* hop_w2     = (const float*)d_in[8];
    const float* hop_b2     = (const float*)d_in[9];
    const float* fn_w1      = (const float*)d_in[10];
    const float* fn_b1      = (const float*)d_in[11];
    const float* fn_w2      = (const float*)d_in[12];
    const float* fn_b2      = (const float*)d_in[13];
    float* out = (float*)d_out;

    float* ws    = (float*)d_ws;
    float* seq   = ws;                    // 49152
    float* eA    = seq   + 49152;         // 49152
    float* xi0   = eA    + 49152;         // 110592
    float* xj0   = xi0   + 110592;
    float* xi1   = xj0   + 110592;
    float* xj1   = xi1   + 110592;
    float* lutlo = xj1   + 110592;        // 2304
    float* luthi = lutlo + 2304;
    float* invD  = luthi + 2304;          // 768
    float* s0    = invD  + 768;           // 1536
    float* s1    = s0    + 1536;          // 1536
    unsigned char* P = (unsigned char*)(s1 + 1536);  // 768*768 bytes

    k1_kernel<<<N_STK, 256, 0, stream>>>(rel, input_data, lstm_Wih, lstm_Whh,
            lstm_bih, lstm_bhh, hop_w1, hop_b1,
            seq, invD, P, lutlo, luthi, xi0, xj0, s0);

    dim3 hgrid(NCR, NPHI, BATCH);
    hop_kernel<<<hgrid, 256, 0, stream>>>(xi0, xj0, lutlo, luthi,
            hop_w2, hop_b2, P, invD, s0);

    ep_kernel<0><<<N_STK, 192, 0, stream>>>(s0, seq, nullptr, eA,
            hop_w1 + INP*INP, xi1, xj1, s1,
            nullptr, nullptr, nullptr, nullptr, nullptr);

    hop_kernel<<<hgrid, 256, 0, stream>>>(xi1, xj1, lutlo + 16*INP, luthi + 16*INP,
            hop_w2 + INP, hop_b2 + 1, P, invD, s1);

    ep_kernel<1><<<N_STK, 192, 0, stream>>>(s1, eA, seq, nullptr,
            nullptr, nullptr, nullptr, nullptr,
            fn_w1, fn_b1, fn_w2, fn_b2, out);
}